// Round 11
// baseline (791.454 us; speedup 1.0000x reference)
//
#include <hip/hip_runtime.h>

constexpr int B_ = 2, N_ = 16384, E_ = 131072, C_ = 128, K_ = 64, FC_ = 128, L_ = 4;

__device__ __forceinline__ float gelu_f(float x) {
    return 0.5f * x * (1.0f + erff(x * 0.70710678118654752f));
}

// ---------------- bases: interleaved bci[b][k][n/2] = {c(n0),c(n1),s(n0),s(n1)}, mask folded ----------------
__global__ __launch_bounds__(256) void bases_kernel(const float* __restrict__ nodes,
                                                    const float* __restrict__ modes,
                                                    const float* __restrict__ node_mask,
                                                    float4* __restrict__ bci) {
    int idx = blockIdx.x * blockDim.x + threadIdx.x;   // B*K*N/2 total
    int n2 = idx & (N_ / 2 - 1);
    int k = (idx >> 13) & (K_ - 1);
    int b = idx >> 19;
    int n0 = n2 * 2;
    float m0x = modes[k * 2 + 0], m1x = modes[k * 2 + 1];
    float a0 = nodes[(b * N_ + n0) * 2 + 0] * m0x + nodes[(b * N_ + n0) * 2 + 1] * m1x;
    float a1 = nodes[(b * N_ + n0 + 1) * 2 + 0] * m0x + nodes[(b * N_ + n0 + 1) * 2 + 1] * m1x;
    float s0, c0, s1, c1;
    sincosf(a0, &s0, &c0);
    sincosf(a1, &s1, &c1);
    float q0 = node_mask[b * N_ + n0];
    float q1 = node_mask[b * N_ + n0 + 1];
    float4 v = { c0 * q0, c1 * q1, s0 * q0, s1 * q1 };
    bci[idx] = v;
}

// ---------------- fc0 ----------------
__global__ __launch_bounds__(256) void fc0_kernel(const float* __restrict__ x,
                                                  const float* __restrict__ w,
                                                  const float* __restrict__ bias,
                                                  float* __restrict__ h) {
    int idx = blockIdx.x * blockDim.x + threadIdx.x;
    int n = idx & (N_ - 1);
    int c = (idx >> 14) & (C_ - 1);
    int b = idx >> 21;
    const float* xr = x + (b * N_ + n) * 3;
    h[idx] = fmaf(xr[0], w[0 * C_ + c], fmaf(xr[1], w[1 * C_ + c], fmaf(xr[2], w[2 * C_ + c], bias[c])));
}

// ---------------- x0 moment ----------------
__global__ __launch_bounds__(256) void x0_kernel(const float* __restrict__ h,
                                                 const float* __restrict__ mask,
                                                 const float* __restrict__ wt,
                                                 double* __restrict__ x0) {
    int bc = blockIdx.x;
    int b = bc >> 7;
    int t = threadIdx.x;
    const float* hr = h + (size_t)bc * N_;
    const float* mr = mask + b * N_;
    const float* wr = wt + b * N_;
    double acc = 0.0;
    for (int n = t; n < N_; n += 256)
        acc += (double)hr[n] * (double)(mr[n] * wr[n]);
    __shared__ double red[256];
    red[t] = acc;
    __syncthreads();
    for (int s = 128; s > 0; s >>= 1) { if (t < s) red[t] += red[t + s]; __syncthreads(); }
    if (t == 0) x0[bc] = red[0];
}

// ---------------- spectral moments: fp32 inner, per-block partial slab ----------------
__global__ __launch_bounds__(256) void moments_kernel(const float* __restrict__ h,
                                                      const float* __restrict__ wt,
                                                      const float4* __restrict__ bci,
                                                      float* __restrict__ pc,
                                                      float* __restrict__ ps) {
    int b = blockIdx.x, ch = blockIdx.y, nz = blockIdx.z;
    int c0 = ch * 64, nbase = nz * 128;
    __shared__ __align__(16) float hw[64][64];
    __shared__ __align__(16) float bcn[64][64];   // [nj][k]
    __shared__ __align__(16) float bsn[64][64];
    int t = threadIdx.x;
    int kp = t & 15, cg = t >> 4;
    float ac[4][4] = {}, as[4][4] = {};   // [c][k]
    #pragma unroll
    for (int chunk = 0; chunk < 2; ++chunk) {
        int n0 = nbase + chunk * 64;
        __syncthreads();
        {
            int ci = t >> 2, ng = (t & 3) * 16;
            const float* hr = h + (size_t)(b * C_ + c0 + ci) * N_ + n0 + ng;
            const float* wr = wt + b * N_ + n0 + ng;
            #pragma unroll
            for (int j = 0; j < 4; ++j) {
                float4 h4 = *(const float4*)(hr + 4 * j);
                float4 w4 = *(const float4*)(wr + 4 * j);
                float4 p = { h4.x * w4.x, h4.y * w4.y, h4.z * w4.z, h4.w * w4.w };
                *(float4*)&hw[ci][ng + 4 * j] = p;
            }
        }
        {
            int kk = t & 63, ng = (t >> 6) * 16;   // 16 n = 8 n-pairs
            const float4* bp = bci + (size_t)(b * K_ + kk) * (N_ / 2) + (n0 + ng) / 2;
            #pragma unroll
            for (int j = 0; j < 8; ++j) {
                float4 v = bp[j];
                bcn[ng + 2 * j + 0][kk] = v.x;
                bcn[ng + 2 * j + 1][kk] = v.y;
                bsn[ng + 2 * j + 0][kk] = v.z;
                bsn[ng + 2 * j + 1][kk] = v.w;
            }
        }
        __syncthreads();
        #pragma unroll 4
        for (int nj = 0; nj < 64; ++nj) {
            float4 bc4 = *(const float4*)&bcn[nj][kp * 4];
            float4 bs4 = *(const float4*)&bsn[nj][kp * 4];
            #pragma unroll
            for (int r = 0; r < 4; ++r) {
                float hv = hw[cg * 4 + r][nj];
                ac[r][0] += hv * bc4.x;
                ac[r][1] += hv * bc4.y;
                ac[r][2] += hv * bc4.z;
                ac[r][3] += hv * bc4.w;
                as[r][0] -= hv * bs4.x;
                as[r][1] -= hv * bs4.y;
                as[r][2] -= hv * bs4.z;
                as[r][3] -= hv * bs4.w;
            }
        }
    }
    size_t base = ((size_t)((b * 2 + ch) * 128 + nz)) * 4096;
    #pragma unroll
    for (int r = 0; r < 4; ++r) {
        float4 vc = { ac[r][0], ac[r][1], ac[r][2], ac[r][3] };
        float4 vs = { as[r][0], as[r][1], as[r][2], as[r][3] };
        *(float4*)&pc[base + (cg * 4 + r) * 64 + kp * 4] = vc;
        *(float4*)&ps[base + (cg * 4 + r) * 64 + kp * 4] = vs;
    }
}

// ---------------- reduce partials -> f64 xc/xs ----------------
__global__ __launch_bounds__(256) void mreduce_kernel(const float* __restrict__ pc,
                                                      const float* __restrict__ ps,
                                                      double* __restrict__ xc,
                                                      double* __restrict__ xs) {
    int e = blockIdx.x * 256 + threadIdx.x;   // (b*C + c)*K + k
    int k = e & 63, c = (e >> 6) & 127, b = e >> 13;
    int ch = c >> 6, cl = c & 63;
    size_t rowbase = ((size_t)(b * 2 + ch) * 128) * 4096 + cl * 64 + k;
    int nz0 = blockIdx.y * 32;
    double sc = 0.0, ss = 0.0;
    for (int nz = nz0; nz < nz0 + 32; ++nz) {
        sc += (double)pc[rowbase + (size_t)nz * 4096];
        ss += (double)ps[rowbase + (size_t)nz * 4096];
    }
    atomicAdd(&xc[e], sc);
    atomicAdd(&xs[e], ss);
}

// ---------------- mode-mix, i-split 8x ----------------
__global__ __launch_bounds__(256) void mix_kernel(const double* __restrict__ xc,
                                                  const double* __restrict__ xs,
                                                  const float* __restrict__ wc,
                                                  const float* __restrict__ ws,
                                                  double* __restrict__ mtc,
                                                  double* __restrict__ mts) {
    int idx = blockIdx.x * blockDim.x + threadIdx.x;   // (b*C + o)*K + k
    int ic = blockIdx.y;
    int k = idx & 63, o = (idx >> 6) & 127, b = idx >> 13;
    double afc = 0.0, afs = 0.0;
    for (int i = ic * 16; i < ic * 16 + 16; ++i) {
        double xcv = xc[(b * C_ + i) * K_ + k], xsv = xs[(b * C_ + i) * K_ + k];
        double wcv = (double)wc[(i * C_ + o) * K_ + k], wsv = (double)ws[(i * C_ + o) * K_ + k];
        afc += xcv * wcv - xsv * wsv;
        afs += xsv * wcv + xcv * wsv;
    }
    mtc[ic * (B_ * C_ * K_) + idx] = afc;
    mts[ic * (B_ * C_ * K_) + idx] = afs;
}

// fc out = +2*sum, fs out = -2*sum (pre-scaled/negated for synth's pure-FMA loop)
__global__ __launch_bounds__(256) void mixfin_kernel(const double* __restrict__ mtc,
                                                     const double* __restrict__ mts,
                                                     float* __restrict__ fc,
                                                     float* __restrict__ fs) {
    int idx = blockIdx.x * blockDim.x + threadIdx.x;
    double a = 0.0, s = 0.0;
    #pragma unroll
    for (int ic = 0; ic < 8; ++ic) {
        a += mtc[ic * (B_ * C_ * K_) + idx];
        s += mts[ic * (B_ * C_ * K_) + idx];
    }
    fc[idx] = (float)(2.0 * a);
    fs[idx] = (float)(-2.0 * s);
}

__global__ __launch_bounds__(256) void mix0_kernel(const double* __restrict__ x0,
                                                   const float* __restrict__ w0,
                                                   float* __restrict__ f0) {
    int idx = threadIdx.x;
    int o = idx & 127, b = idx >> 7;
    double a = 0.0;
    for (int i = 0; i < C_; ++i) a += x0[b * C_ + i] * (double)w0[i * C_ + o];
    f0[idx] = (float)a;
}

// ---------------- synthesis + Conv1d (+ optional fused gelu(W1@h)) ----------------
// NO LDS; interleaved bci (1 float4/kk = both cos&sin at 2n); 2n/thread; grid (B, N/512, C/8).
template <bool FUSE_M>
__global__ __launch_bounds__(256) void synth_kernel(const float* __restrict__ h,
                                                    const float4* __restrict__ bci,
                                                    const float* __restrict__ mask,
                                                    const float* __restrict__ fc,
                                                    const float* __restrict__ fs,
                                                    const float* __restrict__ f0,
                                                    const float* __restrict__ ww,
                                                    const float* __restrict__ wb,
                                                    const float* __restrict__ gw,
                                                    const float* __restrict__ gb,
                                                    float* __restrict__ hnew,
                                                    float* __restrict__ mout) {
    int b = blockIdx.x, n0 = blockIdx.y * 512, o0 = blockIdx.z * 8;
    int t = threadIdx.x;
    int n = n0 + t * 2;
    const float* fcp = fc + (size_t)(b * C_ + o0) * K_;   // [8][K] uniform
    const float* fsp = fs + (size_t)(b * C_ + o0) * K_;
    const float* wwp = ww + (size_t)o0 * C_;              // [8][C] uniform
    const float* gwp = FUSE_M ? gw + (size_t)o0 * C_ : nullptr;
    float2 mv = *(const float2*)(mask + b * N_ + n);
    float acc[8][2];
    float accm[8][2];
    #pragma unroll
    for (int oi = 0; oi < 8; ++oi) {
        float f0v = f0[b * C_ + o0 + oi];
        float wbv = wb[o0 + oi];
        acc[oi][0] = f0v * mv.x + wbv;
        acc[oi][1] = f0v * mv.y + wbv;
        if (FUSE_M) {
            float gbv = gb[o0 + oi];
            accm[oi][0] = gbv;
            accm[oi][1] = gbv;
        }
    }
    const float4* bp = bci + (size_t)b * K_ * (N_ / 2) + (n >> 1);
    #pragma unroll 8
    for (int kk = 0; kk < K_; ++kk) {
        float4 v = bp[(size_t)kk * (N_ / 2)];   // {c(n0), c(n1), s(n0), s(n1)}
        #pragma unroll
        for (int oi = 0; oi < 8; ++oi) {
            float fcv = fcp[oi * K_ + kk];   // uniform -> SGPR
            float fsv = fsp[oi * K_ + kk];   // pre-negated/scaled
            acc[oi][0] += fcv * v.x + fsv * v.z;
            acc[oi][1] += fcv * v.y + fsv * v.w;
        }
    }
    #pragma unroll 8
    for (int ii = 0; ii < C_; ++ii) {
        float2 hv = *(const float2*)(h + (size_t)(b * C_ + ii) * N_ + n);
        #pragma unroll
        for (int oi = 0; oi < 8; ++oi) {
            float wv = wwp[oi * C_ + ii];    // uniform -> SGPR
            acc[oi][0] += wv * hv.x;
            acc[oi][1] += wv * hv.y;
            if (FUSE_M) {
                float gv = gwp[oi * C_ + ii];
                accm[oi][0] += gv * hv.x;
                accm[oi][1] += gv * hv.y;
            }
        }
    }
    #pragma unroll
    for (int oi = 0; oi < 8; ++oi) {
        float2 st = { acc[oi][0], acc[oi][1] };
        *(float2*)(hnew + (size_t)(b * C_ + o0 + oi) * N_ + n) = st;
        if (FUSE_M) {
            float2 sm = { gelu_f(accm[oi][0]), gelu_f(accm[oi][1]) };
            *(float2*)(mout + (size_t)(b * C_ + o0 + oi) * N_ + n) = sm;
        }
    }
}

// ---------------- channel GEMM: out = act(W @ in + b); no LDS, 8 o x 2 n ----------------
// grid (B, N/512, C/8).
template <bool GELU_ACT, bool TRANSPOSED_OUT, bool W_TRANSPOSED>
__global__ __launch_bounds__(256) void cgemm_kernel(const float* __restrict__ in,
                                                    const float* __restrict__ W,
                                                    const float* __restrict__ bias,
                                                    float* __restrict__ out) {
    int b = blockIdx.x, n0 = blockIdx.y * 512, o0 = blockIdx.z * 8;
    int t = threadIdx.x;
    int n = n0 + t * 2;
    float acc[8][2];
    #pragma unroll
    for (int oi = 0; oi < 8; ++oi) {
        float bv = bias[o0 + oi];
        acc[oi][0] = bv;
        acc[oi][1] = bv;
    }
    #pragma unroll 8
    for (int ii = 0; ii < C_; ++ii) {
        float2 v = *(const float2*)(in + (size_t)(b * C_ + ii) * N_ + n);
        #pragma unroll
        for (int oi = 0; oi < 8; ++oi) {
            float wv = W_TRANSPOSED ? W[ii * C_ + (o0 + oi)] : W[(o0 + oi) * C_ + ii];  // uniform
            acc[oi][0] += wv * v.x;
            acc[oi][1] += wv * v.y;
        }
    }
    if (TRANSPOSED_OUT) {
        #pragma unroll
        for (int j = 0; j < 2; ++j) {
            float* orow = out + (size_t)(b * N_ + n + j) * C_ + o0;
            #pragma unroll
            for (int q = 0; q < 2; ++q) {
                float4 v4;
                v4.x = GELU_ACT ? gelu_f(acc[q * 4 + 0][j]) : acc[q * 4 + 0][j];
                v4.y = GELU_ACT ? gelu_f(acc[q * 4 + 1][j]) : acc[q * 4 + 1][j];
                v4.z = GELU_ACT ? gelu_f(acc[q * 4 + 2][j]) : acc[q * 4 + 2][j];
                v4.w = GELU_ACT ? gelu_f(acc[q * 4 + 3][j]) : acc[q * 4 + 3][j];
                *(float4*)(orow + q * 4) = v4;
            }
        }
    } else {
        #pragma unroll
        for (int oi = 0; oi < 8; ++oi) {
            float2 v2;
            v2.x = GELU_ACT ? gelu_f(acc[oi][0]) : acc[oi][0];
            v2.y = GELU_ACT ? gelu_f(acc[oi][1]) : acc[oi][1];
            *(float2*)(out + (size_t)(b * C_ + o0 + oi) * N_ + n) = v2;
        }
    }
}

// ---------------- edge binning (once per call) ----------------
__global__ __launch_bounds__(256) void hist_kernel(const int* __restrict__ edges,
                                                   int* __restrict__ cnt) {
    int be = blockIdx.x * 256 + threadIdx.x;
    int b = be >> 17;
    int tgt = edges[(size_t)be * 2 + 1];
    atomicAdd(&cnt[b * N_ + tgt], 1);
}

__global__ __launch_bounds__(256) void scanA_kernel(const int* __restrict__ cnt,
                                                    int* __restrict__ offs,
                                                    int* __restrict__ bsum) {
    __shared__ int sd[256];
    int t = threadIdx.x;
    int g = blockIdx.x * 256 + t;
    int v = cnt[g];
    sd[t] = v;
    __syncthreads();
    for (int off = 1; off < 256; off <<= 1) {
        int x = (t >= off) ? sd[t - off] : 0;
        __syncthreads();
        sd[t] += x;
        __syncthreads();
    }
    offs[g] = sd[t] - v;
    if (t == 255) bsum[blockIdx.x] = sd[255];
}

__global__ __launch_bounds__(128) void scanB_kernel(const int* __restrict__ bsum,
                                                    int* __restrict__ bbase) {
    __shared__ int sd[128];
    int t = threadIdx.x;
    int v = bsum[t];
    sd[t] = v;
    __syncthreads();
    for (int off = 1; off < 128; off <<= 1) {
        int x = (t >= off) ? sd[t - off] : 0;
        __syncthreads();
        sd[t] += x;
        __syncthreads();
    }
    bbase[t] = sd[t] - v;
}

__global__ __launch_bounds__(256) void scanC_kernel(int* __restrict__ offs,
                                                    const int* __restrict__ bbase) {
    int t = threadIdx.x;
    int g = blockIdx.x * 256 + t;
    offs[g] += bbase[blockIdx.x];
    if (g == 0) offs[B_ * N_] = B_ * E_;
}

__global__ __launch_bounds__(256) void fill_kernel(const int* __restrict__ edges,
                                                   const float* __restrict__ nodes,
                                                   const int* __restrict__ offs,
                                                   int* __restrict__ cursor,
                                                   int* __restrict__ ssrc,
                                                   float2* __restrict__ sef) {
    int be = blockIdx.x * 256 + threadIdx.x;
    int b = be >> 17;
    int src = edges[(size_t)be * 2 + 0];
    int tgt = edges[(size_t)be * 2 + 1];
    int bin = b * N_ + tgt;
    int pos = atomicAdd(&cursor[bin], 1);
    int idx = offs[bin] + pos;
    ssrc[idx] = b * N_ + src;
    float2 ef;
    ef.x = nodes[(size_t)(b * N_ + src) * 2 + 0] - nodes[(size_t)(b * N_ + tgt) * 2 + 0];
    ef.y = nodes[(size_t)(b * N_ + src) * 2 + 1] - nodes[(size_t)(b * N_ + tgt) * 2 + 1];
    sef[idx] = ef;
}

// ---------------- per-layer edge kernel values ----------------
__global__ __launch_bounds__(256) void ker_kernel(const float2* __restrict__ sef,
                                                  const float* __restrict__ isw,
                                                  const float* __restrict__ isb,
                                                  const float* __restrict__ gC,
                                                  int l,
                                                  float* __restrict__ kerb) {
    int m = blockIdx.x * 256 + threadIdx.x;
    float2 ef = sef[m];
    float sig0 = isw[0] * ef.x + isw[1] * ef.y + isb[0];
    float sig1 = isw[2] * ef.x + isw[3] * ef.y + isb[1];
    kerb[m] = gC[l] * expf(ef.x * sig0 + ef.y * sig1);
}

// ---------------- per-target gather: 8 rows/block, float4/thread, 4-edge unroll ----------------
__global__ __launch_bounds__(256) void gather_kernel(const int* __restrict__ offs,
                                                     const int* __restrict__ ssrc,
                                                     const float* __restrict__ kerb,
                                                     const float* __restrict__ ft,
                                                     float* __restrict__ x3t) {
    int t = threadIdx.x;
    int row = blockIdx.x * 8 + (t >> 5);   // b*N + n
    int cq = (t & 31) * 4;
    int start = offs[row], end = offs[row + 1];
    float4 acc = { 0.f, 0.f, 0.f, 0.f };
    int j = start;
    for (; j + 4 <= end; j += 4) {
        int s0 = ssrc[j + 0], s1 = ssrc[j + 1], s2 = ssrc[j + 2], s3 = ssrc[j + 3];
        float k0 = kerb[j + 0], k1 = kerb[j + 1], k2 = kerb[j + 2], k3 = kerb[j + 3];
        float4 v0 = *(const float4*)(ft + (size_t)s0 * C_ + cq);
        float4 v1 = *(const float4*)(ft + (size_t)s1 * C_ + cq);
        float4 v2 = *(const float4*)(ft + (size_t)s2 * C_ + cq);
        float4 v3 = *(const float4*)(ft + (size_t)s3 * C_ + cq);
        acc.x += k0 * v0.x + k1 * v1.x + k2 * v2.x + k3 * v3.x;
        acc.y += k0 * v0.y + k1 * v1.y + k2 * v2.y + k3 * v3.y;
        acc.z += k0 * v0.z + k1 * v1.z + k2 * v2.z + k3 * v3.z;
        acc.w += k0 * v0.w + k1 * v1.w + k2 * v2.w + k3 * v3.w;
    }
    for (; j < end; ++j) {
        int s = ssrc[j];
        float kv = kerb[j];
        float4 v = *(const float4*)(ft + (size_t)s * C_ + cq);
        acc.x += kv * v.x;
        acc.y += kv * v.y;
        acc.z += kv * v.z;
        acc.w += kv * v.w;
    }
    *(float4*)(x3t + (size_t)row * C_ + cq) = acc;
}

// ---------------- combine: h = gelu(hnew) + gelu(x3t^T) ----------------
__global__ __launch_bounds__(256) void combine_kernel(const float* __restrict__ hnew,
                                                      const float* __restrict__ x3t,
                                                      float* __restrict__ h) {
    int b = blockIdx.x, c0 = blockIdx.y * 32, n0 = blockIdx.z * 64;
    __shared__ float tl[32][65];
    int t = threadIdx.x;
    int ci = t & 31, nj = t >> 5;
    #pragma unroll
    for (int p = 0; p < 8; ++p) {
        int n = n0 + p * 8 + nj;
        tl[ci][p * 8 + nj] = x3t[(size_t)(b * N_ + n) * C_ + c0 + ci];
    }
    __syncthreads();
    int nj2 = t & 63, ci2 = t >> 6;
    #pragma unroll
    for (int p = 0; p < 8; ++p) {
        int c = c0 + p * 4 + ci2;
        int idx = (b * C_ + c) * N_ + n0 + nj2;
        h[idx] = gelu_f(hnew[idx]) + gelu_f(tl[p * 4 + ci2][nj2]);
    }
}

// ---------------- final fc2 contraction ----------------
__global__ __launch_bounds__(256) void f2_kernel(const float* __restrict__ y1,
                                                 const float* __restrict__ w2,
                                                 const float* __restrict__ b2,
                                                 float* __restrict__ out) {
    int idx = blockIdx.x * blockDim.x + threadIdx.x;
    int n = idx & (N_ - 1), b = idx >> 14;
    float acc = b2[0];
    for (int f = 0; f < FC_; ++f) acc += y1[(b * FC_ + f) * N_ + n] * w2[f];
    out[idx] = acc;
}

extern "C" void kernel_launch(void* const* d_in, const int* in_sizes, int n_in,
                              void* d_out, int out_size, void* d_ws, size_t ws_size,
                              hipStream_t stream) {
    const float* x         = (const float*)d_in[0];
    const float* node_mask = (const float*)d_in[1];
    const float* nodes     = (const float*)d_in[2];
    const float* node_w    = (const float*)d_in[3];
    const int*   edges     = (const int*)d_in[4];
    const float* modes     = (const float*)d_in[5];
    const float* fc0_w     = (const float*)d_in[6];
    const float* fc0_b     = (const float*)d_in[7];
    const float* sp_wc     = (const float*)d_in[8];
    const float* sp_ws     = (const float*)d_in[9];
    const float* sp_w0     = (const float*)d_in[10];
    const float* w_w       = (const float*)d_in[11];
    const float* w_b       = (const float*)d_in[12];
    const float* g_w1      = (const float*)d_in[13];
    const float* g_b1      = (const float*)d_in[14];
    const float* g_w2      = (const float*)d_in[15];
    const float* g_b2      = (const float*)d_in[16];
    const float* isw       = (const float*)d_in[17];
    const float* isb       = (const float*)d_in[18];
    const float* gC        = (const float*)d_in[19];
    const float* fc1_w     = (const float*)d_in[20];
    const float* fc1_b     = (const float*)d_in[21];
    const float* fc2_w     = (const float*)d_in[22];
    const float* fc2_b     = (const float*)d_in[23];
    float* out = (float*)d_out;

    // ---- workspace layout ----
    float4* bci = (float4*)d_ws;                         // B*K*N/2 float4 = 4M floats
    float* h    = (float*)d_ws + (size_t)B_ * K_ * N_ * 2;   // 4M floats
    float* hnew = h + (size_t)B_ * C_ * N_;              // 4M
    float* mbuf = hnew + (size_t)B_ * C_ * N_;           // 4M
    double* xc  = (double*)(mbuf + (size_t)B_ * C_ * N_);
    double* xs  = xc + B_ * C_ * K_;
    double* x0  = xs + B_ * C_ * K_;                     // 256
    double* mtc = x0 + 256;                              // 8*16384
    double* mts = mtc + 8 * B_ * C_ * K_;
    float2* sef = (float2*)(mts + 8 * B_ * C_ * K_);     // B*E float2
    float* fcb  = (float*)(sef + (size_t)B_ * E_);
    float* fsb  = fcb + B_ * C_ * K_;
    float* f0b  = fsb + B_ * C_ * K_;                    // 256
    float* kerb = f0b + 256;                             // B*E
    int* offs   = (int*)(kerb + (size_t)B_ * E_);        // B*N+1 (+pad)
    int* cnt    = offs + B_ * N_ + 4;
    int* cursor = cnt + B_ * N_;
    int* bsum   = cursor + B_ * N_;                      // 128
    int* bbase  = bsum + 128;                            // 128
    int* ssrc   = bbase + 128;                           // B*E
    float* ft   = h;      // alias: h dead when ft is written
    float* x3t  = mbuf;   // alias: mbuf dead when x3t written
    float* pc   = hnew;   // moments partial slabs alias hnew
    float* ps   = hnew + (size_t)B_ * C_ * K_ * 128 / 64;

    dim3 blk(256);

    bases_kernel<<<dim3((B_ * K_ * N_ / 2) / 256), blk, 0, stream>>>(nodes, modes, node_mask, bci);
    fc0_kernel<<<dim3((B_ * C_ * N_) / 256), blk, 0, stream>>>(x, fc0_w, fc0_b, h);

    // ---- edge binning (once) ----
    hipMemsetAsync(cnt, 0, sizeof(int) * B_ * N_, stream);
    hist_kernel<<<dim3(B_ * E_ / 256), blk, 0, stream>>>(edges, cnt);
    scanA_kernel<<<dim3(B_ * N_ / 256), blk, 0, stream>>>(cnt, offs, bsum);
    scanB_kernel<<<dim3(1), dim3(128), 0, stream>>>(bsum, bbase);
    scanC_kernel<<<dim3(B_ * N_ / 256), blk, 0, stream>>>(offs, bbase);
    hipMemsetAsync(cursor, 0, sizeof(int) * B_ * N_, stream);
    fill_kernel<<<dim3(B_ * E_ / 256), blk, 0, stream>>>(edges, nodes, offs, cursor, ssrc, sef);

    for (int l = 0; l < L_; ++l) {
        hipMemsetAsync(xc, 0, sizeof(double) * (size_t)B_ * C_ * K_ * 2, stream);
        moments_kernel<<<dim3(B_, 2, N_ / 128), blk, 0, stream>>>(h, node_w, bci, pc, ps);
        mreduce_kernel<<<dim3(B_ * C_ * K_ / 256, 4), blk, 0, stream>>>(pc, ps, xc, xs);
        x0_kernel<<<dim3(B_ * C_), blk, 0, stream>>>(h, node_mask, node_w, x0);
        mix_kernel<<<dim3(B_ * C_ * K_ / 256, 8), blk, 0, stream>>>(
            xc, xs, sp_wc + (size_t)l * C_ * C_ * K_, sp_ws + (size_t)l * C_ * C_ * K_, mtc, mts);
        mixfin_kernel<<<dim3(B_ * C_ * K_ / 256), blk, 0, stream>>>(mtc, mts, fcb, fsb);
        mix0_kernel<<<dim3(1), blk, 0, stream>>>(x0, sp_w0 + (size_t)l * C_ * C_, f0b);
        if (l != L_ - 1) {
            // fused: hnew = synth, mbuf = gelu(g_w1 @ h + g_b1)
            synth_kernel<true><<<dim3(B_, N_ / 512, C_ / 8), blk, 0, stream>>>(
                h, bci, node_mask, fcb, fsb, f0b, w_w + l * C_ * C_, w_b + l * C_,
                g_w1 + l * C_ * C_, g_b1 + l * C_, hnew, mbuf);
            cgemm_kernel<false, true, false><<<dim3(B_, N_ / 512, C_ / 8), blk, 0, stream>>>(
                mbuf, g_w2 + l * C_ * C_, g_b2 + l * C_, ft);
            ker_kernel<<<dim3(B_ * E_ / 256), blk, 0, stream>>>(sef, isw + l * 4, isb + l * 2, gC, l, kerb);
            gather_kernel<<<dim3(B_ * N_ / 8), blk, 0, stream>>>(offs, ssrc, kerb, ft, x3t);
            combine_kernel<<<dim3(B_, C_ / 32, N_ / 64), blk, 0, stream>>>(hnew, x3t, h);
        } else {
            synth_kernel<false><<<dim3(B_, N_ / 512, C_ / 8), blk, 0, stream>>>(
                h, bci, node_mask, fcb, fsb, f0b, w_w + l * C_ * C_, w_b + l * C_,
                g_w1, g_b1, hnew, mbuf);
        }
    }
    cgemm_kernel<true, false, true><<<dim3(B_, N_ / 512, C_ / 8), blk, 0, stream>>>(
        hnew, fc1_w, fc1_b, h);
    f2_kernel<<<dim3(B_ * N_ / 256), blk, 0, stream>>>(h, fc2_w, fc2_b, out);
}

// Round 12
// 688.150 us; speedup vs baseline: 1.1501x; 1.1501x over previous
//
#include <hip/hip_runtime.h>

constexpr int B_ = 2, N_ = 16384, E_ = 131072, C_ = 128, K_ = 64, FC_ = 128, L_ = 4;

__device__ __forceinline__ float gelu_f(float x) {
    return 0.5f * x * (1.0f + erff(x * 0.70710678118654752f));
}

// ---------------- bases: bc_t/bs_t in (B,K,N) layout, mask folded in ----------------
__global__ __launch_bounds__(256) void bases_kernel(const float* __restrict__ nodes,
                                                    const float* __restrict__ modes,
                                                    const float* __restrict__ node_mask,
                                                    float* __restrict__ bc_t,
                                                    float* __restrict__ bs_t) {
    int idx = blockIdx.x * blockDim.x + threadIdx.x;
    int n = idx & (N_ - 1);
    int k = (idx >> 14) & (K_ - 1);
    int b = idx >> 20;
    float n0 = nodes[(b * N_ + n) * 2 + 0];
    float n1 = nodes[(b * N_ + n) * 2 + 1];
    float t = n0 * modes[k * 2 + 0] + n1 * modes[k * 2 + 1];
    float s, c;
    sincosf(t, &s, &c);
    float m = node_mask[b * N_ + n];
    bc_t[idx] = c * m;
    bs_t[idx] = s * m;
}

// ---------------- fc0 ----------------
__global__ __launch_bounds__(256) void fc0_kernel(const float* __restrict__ x,
                                                  const float* __restrict__ w,
                                                  const float* __restrict__ bias,
                                                  float* __restrict__ h) {
    int idx = blockIdx.x * blockDim.x + threadIdx.x;
    int n = idx & (N_ - 1);
    int c = (idx >> 14) & (C_ - 1);
    int b = idx >> 21;
    const float* xr = x + (b * N_ + n) * 3;
    h[idx] = fmaf(xr[0], w[0 * C_ + c], fmaf(xr[1], w[1 * C_ + c], fmaf(xr[2], w[2 * C_ + c], bias[c])));
}

// ---------------- x0 moment ----------------
__global__ __launch_bounds__(256) void x0_kernel(const float* __restrict__ h,
                                                 const float* __restrict__ mask,
                                                 const float* __restrict__ wt,
                                                 double* __restrict__ x0) {
    int bc = blockIdx.x;
    int b = bc >> 7;
    int t = threadIdx.x;
    const float* hr = h + (size_t)bc * N_;
    const float* mr = mask + b * N_;
    const float* wr = wt + b * N_;
    double acc = 0.0;
    for (int n = t; n < N_; n += 256)
        acc += (double)hr[n] * (double)(mr[n] * wr[n]);
    __shared__ double red[256];
    red[t] = acc;
    __syncthreads();
    for (int s = 128; s > 0; s >>= 1) { if (t < s) red[t] += red[t + s]; __syncthreads(); }
    if (t == 0) x0[bc] = red[0];
}

// ---------------- spectral moments: fp32 inner, per-block partial slab ----------------
__global__ __launch_bounds__(256) void moments_kernel(const float* __restrict__ h,
                                                      const float* __restrict__ wt,
                                                      const float* __restrict__ bc_t,
                                                      const float* __restrict__ bs_t,
                                                      float* __restrict__ pc,
                                                      float* __restrict__ ps) {
    int b = blockIdx.x, ch = blockIdx.y, nz = blockIdx.z;
    int c0 = ch * 64, nbase = nz * 128;
    __shared__ __align__(16) float hw[64][64];
    __shared__ __align__(16) float bcn[64][64];   // [nj][k]
    __shared__ __align__(16) float bsn[64][64];
    int t = threadIdx.x;
    int kp = t & 15, cg = t >> 4;
    float ac[4][4] = {}, as[4][4] = {};   // [c][k]
    #pragma unroll
    for (int chunk = 0; chunk < 2; ++chunk) {
        int n0 = nbase + chunk * 64;
        __syncthreads();
        {
            int ci = t >> 2, ng = (t & 3) * 16;
            const float* hr = h + (size_t)(b * C_ + c0 + ci) * N_ + n0 + ng;
            const float* wr = wt + b * N_ + n0 + ng;
            #pragma unroll
            for (int j = 0; j < 4; ++j) {
                float4 h4 = *(const float4*)(hr + 4 * j);
                float4 w4 = *(const float4*)(wr + 4 * j);
                float4 p = { h4.x * w4.x, h4.y * w4.y, h4.z * w4.z, h4.w * w4.w };
                *(float4*)&hw[ci][ng + 4 * j] = p;
            }
        }
        {
            int kk = t & 63, ng = (t >> 6) * 16;
            const float* bcr = bc_t + (size_t)(b * K_ + kk) * N_ + n0 + ng;
            const float* bsr = bs_t + (size_t)(b * K_ + kk) * N_ + n0 + ng;
            #pragma unroll
            for (int j = 0; j < 4; ++j) {
                float4 vc = *(const float4*)(bcr + 4 * j);
                float4 vs = *(const float4*)(bsr + 4 * j);
                bcn[ng + 4 * j + 0][kk] = vc.x;
                bcn[ng + 4 * j + 1][kk] = vc.y;
                bcn[ng + 4 * j + 2][kk] = vc.z;
                bcn[ng + 4 * j + 3][kk] = vc.w;
                bsn[ng + 4 * j + 0][kk] = vs.x;
                bsn[ng + 4 * j + 1][kk] = vs.y;
                bsn[ng + 4 * j + 2][kk] = vs.z;
                bsn[ng + 4 * j + 3][kk] = vs.w;
            }
        }
        __syncthreads();
        #pragma unroll 4
        for (int nj = 0; nj < 64; ++nj) {
            float4 bc4 = *(const float4*)&bcn[nj][kp * 4];
            float4 bs4 = *(const float4*)&bsn[nj][kp * 4];
            #pragma unroll
            for (int r = 0; r < 4; ++r) {
                float hv = hw[cg * 4 + r][nj];
                ac[r][0] += hv * bc4.x;
                ac[r][1] += hv * bc4.y;
                ac[r][2] += hv * bc4.z;
                ac[r][3] += hv * bc4.w;
                as[r][0] -= hv * bs4.x;
                as[r][1] -= hv * bs4.y;
                as[r][2] -= hv * bs4.z;
                as[r][3] -= hv * bs4.w;
            }
        }
    }
    size_t base = ((size_t)((b * 2 + ch) * 128 + nz)) * 4096;
    #pragma unroll
    for (int r = 0; r < 4; ++r) {
        float4 vc = { ac[r][0], ac[r][1], ac[r][2], ac[r][3] };
        float4 vs = { as[r][0], as[r][1], as[r][2], as[r][3] };
        *(float4*)&pc[base + (cg * 4 + r) * 64 + kp * 4] = vc;
        *(float4*)&ps[base + (cg * 4 + r) * 64 + kp * 4] = vs;
    }
}

// ---------------- reduce partials -> f64 xc/xs ----------------
__global__ __launch_bounds__(256) void mreduce_kernel(const float* __restrict__ pc,
                                                      const float* __restrict__ ps,
                                                      double* __restrict__ xc,
                                                      double* __restrict__ xs) {
    int e = blockIdx.x * 256 + threadIdx.x;   // (b*C + c)*K + k
    int k = e & 63, c = (e >> 6) & 127, b = e >> 13;
    int ch = c >> 6, cl = c & 63;
    size_t rowbase = ((size_t)(b * 2 + ch) * 128) * 4096 + cl * 64 + k;
    int nz0 = blockIdx.y * 32;
    double sc = 0.0, ss = 0.0;
    for (int nz = nz0; nz < nz0 + 32; ++nz) {
        sc += (double)pc[rowbase + (size_t)nz * 4096];
        ss += (double)ps[rowbase + (size_t)nz * 4096];
    }
    atomicAdd(&xc[e], sc);
    atomicAdd(&xs[e], ss);
}

// ---------------- mode-mix, i-split 8x; fp32 inner (16-term chunks), f64 partial out ----------------
__global__ __launch_bounds__(256) void mix_kernel(const double* __restrict__ xc,
                                                  const double* __restrict__ xs,
                                                  const float* __restrict__ wc,
                                                  const float* __restrict__ ws,
                                                  double* __restrict__ mtc,
                                                  double* __restrict__ mts) {
    int idx = blockIdx.x * blockDim.x + threadIdx.x;   // (b*C + o)*K + k
    int ic = blockIdx.y;
    int k = idx & 63, o = (idx >> 6) & 127, b = idx >> 13;
    float afc = 0.0f, afs = 0.0f;
    #pragma unroll 4
    for (int i = ic * 16; i < ic * 16 + 16; ++i) {
        float xcv = (float)xc[(b * C_ + i) * K_ + k], xsv = (float)xs[(b * C_ + i) * K_ + k];
        float wcv = wc[(i * C_ + o) * K_ + k], wsv = ws[(i * C_ + o) * K_ + k];
        afc += xcv * wcv - xsv * wsv;
        afs += xsv * wcv + xcv * wsv;
    }
    mtc[ic * (B_ * C_ * K_) + idx] = (double)afc;
    mts[ic * (B_ * C_ * K_) + idx] = (double)afs;
}

// fc out = +2*sum, fs out = -2*sum (pre-scaled/negated for synth's pure-FMA loop)
__global__ __launch_bounds__(256) void mixfin_kernel(const double* __restrict__ mtc,
                                                     const double* __restrict__ mts,
                                                     float* __restrict__ fc,
                                                     float* __restrict__ fs) {
    int idx = blockIdx.x * blockDim.x + threadIdx.x;
    double a = 0.0, s = 0.0;
    #pragma unroll
    for (int ic = 0; ic < 8; ++ic) {
        a += mtc[ic * (B_ * C_ * K_) + idx];
        s += mts[ic * (B_ * C_ * K_) + idx];
    }
    fc[idx] = (float)(2.0 * a);
    fs[idx] = (float)(-2.0 * s);
}

__global__ __launch_bounds__(256) void mix0_kernel(const double* __restrict__ x0,
                                                   const float* __restrict__ w0,
                                                   float* __restrict__ f0) {
    int idx = threadIdx.x;
    int o = idx & 127, b = idx >> 7;
    double a = 0.0;
    for (int i = 0; i < C_; ++i) a += x0[b * C_ + i] * (double)w0[i * C_ + o];
    f0[idx] = (float)a;
}

// ---------------- synthesis + Conv1d (+ optional fused gelu(W1@h)) ----------------
// NO LDS: coefficients read via wave-uniform global addresses -> s_load/SGPR.
// grid (B, N/512, C/8), 2n/thread float2.   [round-9 exact — do not perturb]
template <bool FUSE_M>
__global__ __launch_bounds__(256) void synth_kernel(const float* __restrict__ h,
                                                    const float* __restrict__ bc_t,
                                                    const float* __restrict__ bs_t,
                                                    const float* __restrict__ mask,
                                                    const float* __restrict__ fc,
                                                    const float* __restrict__ fs,
                                                    const float* __restrict__ f0,
                                                    const float* __restrict__ ww,
                                                    const float* __restrict__ wb,
                                                    const float* __restrict__ gw,
                                                    const float* __restrict__ gb,
                                                    float* __restrict__ hnew,
                                                    float* __restrict__ mout) {
    int b = blockIdx.x, n0 = blockIdx.y * 512, o0 = blockIdx.z * 8;
    int t = threadIdx.x;
    int n = n0 + t * 2;
    const float* fcp = fc + (size_t)(b * C_ + o0) * K_;   // [8][K] uniform
    const float* fsp = fs + (size_t)(b * C_ + o0) * K_;
    const float* wwp = ww + (size_t)o0 * C_;              // [8][C] uniform
    const float* gwp = FUSE_M ? gw + (size_t)o0 * C_ : nullptr;
    float2 mv = *(const float2*)(mask + b * N_ + n);
    float acc[8][2];
    float accm[8][2];
    #pragma unroll
    for (int oi = 0; oi < 8; ++oi) {
        float f0v = f0[b * C_ + o0 + oi];
        float wbv = wb[o0 + oi];
        acc[oi][0] = f0v * mv.x + wbv;
        acc[oi][1] = f0v * mv.y + wbv;
        if (FUSE_M) {
            float gbv = gb[o0 + oi];
            accm[oi][0] = gbv;
            accm[oi][1] = gbv;
        }
    }
    #pragma unroll 4
    for (int kk = 0; kk < K_; ++kk) {
        float2 bc2 = *(const float2*)(bc_t + (size_t)(b * K_ + kk) * N_ + n);
        float2 bs2 = *(const float2*)(bs_t + (size_t)(b * K_ + kk) * N_ + n);
        #pragma unroll
        for (int oi = 0; oi < 8; ++oi) {
            float fcv = fcp[oi * K_ + kk];   // uniform -> SGPR
            float fsv = fsp[oi * K_ + kk];   // pre-negated/scaled
            acc[oi][0] += fcv * bc2.x + fsv * bs2.x;
            acc[oi][1] += fcv * bc2.y + fsv * bs2.y;
        }
    }
    #pragma unroll 4
    for (int ii = 0; ii < C_; ++ii) {
        float2 hv = *(const float2*)(h + (size_t)(b * C_ + ii) * N_ + n);
        #pragma unroll
        for (int oi = 0; oi < 8; ++oi) {
            float wv = wwp[oi * C_ + ii];    // uniform -> SGPR
            acc[oi][0] += wv * hv.x;
            acc[oi][1] += wv * hv.y;
            if (FUSE_M) {
                float gv = gwp[oi * C_ + ii];
                accm[oi][0] += gv * hv.x;
                accm[oi][1] += gv * hv.y;
            }
        }
    }
    #pragma unroll
    for (int oi = 0; oi < 8; ++oi) {
        float2 st = { acc[oi][0], acc[oi][1] };
        *(float2*)(hnew + (size_t)(b * C_ + o0 + oi) * N_ + n) = st;
        if (FUSE_M) {
            float2 sm = { gelu_f(accm[oi][0]), gelu_f(accm[oi][1]) };
            *(float2*)(mout + (size_t)(b * C_ + o0 + oi) * N_ + n) = sm;
        }
    }
}

// ---------------- channel GEMM: out = act(W @ in + b); no LDS, uniform scalar W ----------------
// grid (B, N/512, C/8).   [round-9 exact]
template <bool GELU_ACT, bool TRANSPOSED_OUT, bool W_TRANSPOSED>
__global__ __launch_bounds__(256) void cgemm_kernel(const float* __restrict__ in,
                                                    const float* __restrict__ W,
                                                    const float* __restrict__ bias,
                                                    float* __restrict__ out) {
    int b = blockIdx.x, n0 = blockIdx.y * 512, o0 = blockIdx.z * 8;
    int t = threadIdx.x;
    int n = n0 + t * 2;
    float acc[8][2];
    #pragma unroll
    for (int oi = 0; oi < 8; ++oi) {
        float bv = bias[o0 + oi];
        acc[oi][0] = bv;
        acc[oi][1] = bv;
    }
    #pragma unroll 4
    for (int ii = 0; ii < C_; ++ii) {
        float2 v = *(const float2*)(in + (size_t)(b * C_ + ii) * N_ + n);
        #pragma unroll
        for (int oi = 0; oi < 8; ++oi) {
            float wv = W_TRANSPOSED ? W[ii * C_ + (o0 + oi)] : W[(o0 + oi) * C_ + ii];  // uniform
            acc[oi][0] += wv * v.x;
            acc[oi][1] += wv * v.y;
        }
    }
    if (TRANSPOSED_OUT) {
        #pragma unroll
        for (int j = 0; j < 2; ++j) {
            float* orow = out + (size_t)(b * N_ + n + j) * C_ + o0;
            #pragma unroll
            for (int q = 0; q < 2; ++q) {
                float4 v4;
                v4.x = GELU_ACT ? gelu_f(acc[q * 4 + 0][j]) : acc[q * 4 + 0][j];
                v4.y = GELU_ACT ? gelu_f(acc[q * 4 + 1][j]) : acc[q * 4 + 1][j];
                v4.z = GELU_ACT ? gelu_f(acc[q * 4 + 2][j]) : acc[q * 4 + 2][j];
                v4.w = GELU_ACT ? gelu_f(acc[q * 4 + 3][j]) : acc[q * 4 + 3][j];
                *(float4*)(orow + q * 4) = v4;
            }
        }
    } else {
        #pragma unroll
        for (int oi = 0; oi < 8; ++oi) {
            float2 v2;
            v2.x = GELU_ACT ? gelu_f(acc[oi][0]) : acc[oi][0];
            v2.y = GELU_ACT ? gelu_f(acc[oi][1]) : acc[oi][1];
            *(float2*)(out + (size_t)(b * C_ + o0 + oi) * N_ + n) = v2;
        }
    }
}

// ---------------- edge binning (once per call) ----------------
__global__ __launch_bounds__(256) void hist_kernel(const int* __restrict__ edges,
                                                   int* __restrict__ cnt) {
    int be = blockIdx.x * 256 + threadIdx.x;
    int b = be >> 17;
    int tgt = edges[(size_t)be * 2 + 1];
    atomicAdd(&cnt[b * N_ + tgt], 1);
}

__global__ __launch_bounds__(256) void scanA_kernel(const int* __restrict__ cnt,
                                                    int* __restrict__ offs,
                                                    int* __restrict__ bsum) {
    __shared__ int sd[256];
    int t = threadIdx.x;
    int g = blockIdx.x * 256 + t;
    int v = cnt[g];
    sd[t] = v;
    __syncthreads();
    for (int off = 1; off < 256; off <<= 1) {
        int x = (t >= off) ? sd[t - off] : 0;
        __syncthreads();
        sd[t] += x;
        __syncthreads();
    }
    offs[g] = sd[t] - v;
    if (t == 255) bsum[blockIdx.x] = sd[255];
}

__global__ __launch_bounds__(128) void scanB_kernel(const int* __restrict__ bsum,
                                                    int* __restrict__ bbase) {
    __shared__ int sd[128];
    int t = threadIdx.x;
    int v = bsum[t];
    sd[t] = v;
    __syncthreads();
    for (int off = 1; off < 128; off <<= 1) {
        int x = (t >= off) ? sd[t - off] : 0;
        __syncthreads();
        sd[t] += x;
        __syncthreads();
    }
    bbase[t] = sd[t] - v;
}

__global__ __launch_bounds__(256) void scanC_kernel(int* __restrict__ offs,
                                                    const int* __restrict__ bbase) {
    int t = threadIdx.x;
    int g = blockIdx.x * 256 + t;
    offs[g] += bbase[blockIdx.x];
    if (g == 0) offs[B_ * N_] = B_ * E_;
}

__global__ __launch_bounds__(256) void fill_kernel(const int* __restrict__ edges,
                                                   const float* __restrict__ nodes,
                                                   const int* __restrict__ offs,
                                                   int* __restrict__ cursor,
                                                   int* __restrict__ ssrc,
                                                   float2* __restrict__ sef) {
    int be = blockIdx.x * 256 + threadIdx.x;
    int b = be >> 17;
    int src = edges[(size_t)be * 2 + 0];
    int tgt = edges[(size_t)be * 2 + 1];
    int bin = b * N_ + tgt;
    int pos = atomicAdd(&cursor[bin], 1);
    int idx = offs[bin] + pos;
    ssrc[idx] = b * N_ + src;
    float2 ef;
    ef.x = nodes[(size_t)(b * N_ + src) * 2 + 0] - nodes[(size_t)(b * N_ + tgt) * 2 + 0];
    ef.y = nodes[(size_t)(b * N_ + src) * 2 + 1] - nodes[(size_t)(b * N_ + tgt) * 2 + 1];
    sef[idx] = ef;
}

// ---------------- per-layer edge kernel values ----------------
__global__ __launch_bounds__(256) void ker_kernel(const float2* __restrict__ sef,
                                                  const float* __restrict__ isw,
                                                  const float* __restrict__ isb,
                                                  const float* __restrict__ gC,
                                                  int l,
                                                  float* __restrict__ kerb) {
    int m = blockIdx.x * 256 + threadIdx.x;
    float2 ef = sef[m];
    float sig0 = isw[0] * ef.x + isw[1] * ef.y + isb[0];
    float sig1 = isw[2] * ef.x + isw[3] * ef.y + isb[1];
    kerb[m] = gC[l] * expf(ef.x * sig0 + ef.y * sig1);
}

// ---------------- per-target gather: 8 rows/block, float4/thread, 4-edge unroll ----------------
__global__ __launch_bounds__(256) void gather_kernel(const int* __restrict__ offs,
                                                     const int* __restrict__ ssrc,
                                                     const float* __restrict__ kerb,
                                                     const float* __restrict__ ft,
                                                     float* __restrict__ x3t) {
    int t = threadIdx.x;
    int row = blockIdx.x * 8 + (t >> 5);   // b*N + n
    int cq = (t & 31) * 4;
    int start = offs[row], end = offs[row + 1];
    float4 acc = { 0.f, 0.f, 0.f, 0.f };
    int j = start;
    for (; j + 4 <= end; j += 4) {
        int s0 = ssrc[j + 0], s1 = ssrc[j + 1], s2 = ssrc[j + 2], s3 = ssrc[j + 3];
        float k0 = kerb[j + 0], k1 = kerb[j + 1], k2 = kerb[j + 2], k3 = kerb[j + 3];
        float4 v0 = *(const float4*)(ft + (size_t)s0 * C_ + cq);
        float4 v1 = *(const float4*)(ft + (size_t)s1 * C_ + cq);
        float4 v2 = *(const float4*)(ft + (size_t)s2 * C_ + cq);
        float4 v3 = *(const float4*)(ft + (size_t)s3 * C_ + cq);
        acc.x += k0 * v0.x + k1 * v1.x + k2 * v2.x + k3 * v3.x;
        acc.y += k0 * v0.y + k1 * v1.y + k2 * v2.y + k3 * v3.y;
        acc.z += k0 * v0.z + k1 * v1.z + k2 * v2.z + k3 * v3.z;
        acc.w += k0 * v0.w + k1 * v1.w + k2 * v2.w + k3 * v3.w;
    }
    for (; j < end; ++j) {
        int s = ssrc[j];
        float kv = kerb[j];
        float4 v = *(const float4*)(ft + (size_t)s * C_ + cq);
        acc.x += kv * v.x;
        acc.y += kv * v.y;
        acc.z += kv * v.z;
        acc.w += kv * v.w;
    }
    *(float4*)(x3t + (size_t)row * C_ + cq) = acc;
}

// ---------------- combine: h = gelu(hnew) + gelu(x3t^T) ----------------
__global__ __launch_bounds__(256) void combine_kernel(const float* __restrict__ hnew,
                                                      const float* __restrict__ x3t,
                                                      float* __restrict__ h) {
    int b = blockIdx.x, c0 = blockIdx.y * 32, n0 = blockIdx.z * 64;
    __shared__ float tl[32][65];
    int t = threadIdx.x;
    int ci = t & 31, nj = t >> 5;
    #pragma unroll
    for (int p = 0; p < 8; ++p) {
        int n = n0 + p * 8 + nj;
        tl[ci][p * 8 + nj] = x3t[(size_t)(b * N_ + n) * C_ + c0 + ci];
    }
    __syncthreads();
    int nj2 = t & 63, ci2 = t >> 6;
    #pragma unroll
    for (int p = 0; p < 8; ++p) {
        int c = c0 + p * 4 + ci2;
        int idx = (b * C_ + c) * N_ + n0 + nj2;
        h[idx] = gelu_f(hnew[idx]) + gelu_f(tl[p * 4 + ci2][nj2]);
    }
}

// ---------------- final fc2 contraction ----------------
__global__ __launch_bounds__(256) void f2_kernel(const float* __restrict__ y1,
                                                 const float* __restrict__ w2,
                                                 const float* __restrict__ b2,
                                                 float* __restrict__ out) {
    int idx = blockIdx.x * blockDim.x + threadIdx.x;
    int n = idx & (N_ - 1), b = idx >> 14;
    float acc = b2[0];
    for (int f = 0; f < FC_; ++f) acc += y1[(b * FC_ + f) * N_ + n] * w2[f];
    out[idx] = acc;
}

extern "C" void kernel_launch(void* const* d_in, const int* in_sizes, int n_in,
                              void* d_out, int out_size, void* d_ws, size_t ws_size,
                              hipStream_t stream) {
    const float* x         = (const float*)d_in[0];
    const float* node_mask = (const float*)d_in[1];
    const float* nodes     = (const float*)d_in[2];
    const float* node_w    = (const float*)d_in[3];
    const int*   edges     = (const int*)d_in[4];
    const float* modes     = (const float*)d_in[5];
    const float* fc0_w     = (const float*)d_in[6];
    const float* fc0_b     = (const float*)d_in[7];
    const float* sp_wc     = (const float*)d_in[8];
    const float* sp_ws     = (const float*)d_in[9];
    const float* sp_w0     = (const float*)d_in[10];
    const float* w_w       = (const float*)d_in[11];
    const float* w_b       = (const float*)d_in[12];
    const float* g_w1      = (const float*)d_in[13];
    const float* g_b1      = (const float*)d_in[14];
    const float* g_w2      = (const float*)d_in[15];
    const float* g_b2      = (const float*)d_in[16];
    const float* isw       = (const float*)d_in[17];
    const float* isb       = (const float*)d_in[18];
    const float* gC        = (const float*)d_in[19];
    const float* fc1_w     = (const float*)d_in[20];
    const float* fc1_b     = (const float*)d_in[21];
    const float* fc2_w     = (const float*)d_in[22];
    const float* fc2_b     = (const float*)d_in[23];
    float* out = (float*)d_out;

    // ---- workspace layout ----
    float* bc_t = (float*)d_ws;                          // 2M floats
    float* bs_t = bc_t + (size_t)B_ * K_ * N_;           // 2M
    float* h    = bs_t + (size_t)B_ * K_ * N_;           // 4M
    float* hnew = h + (size_t)B_ * C_ * N_;              // 4M
    float* mbuf = hnew + (size_t)B_ * C_ * N_;           // 4M
    double* xc  = (double*)(mbuf + (size_t)B_ * C_ * N_);
    double* xs  = xc + B_ * C_ * K_;
    double* x0  = xs + B_ * C_ * K_;                     // 256
    double* mtc = x0 + 256;                              // 8*16384
    double* mts = mtc + 8 * B_ * C_ * K_;
    float2* sef = (float2*)(mts + 8 * B_ * C_ * K_);     // B*E float2
    float* fcb  = (float*)(sef + (size_t)B_ * E_);
    float* fsb  = fcb + B_ * C_ * K_;
    float* f0b  = fsb + B_ * C_ * K_;                    // 256
    float* kerb = f0b + 256;                             // B*E
    int* offs   = (int*)(kerb + (size_t)B_ * E_);        // B*N+1 (+pad)
    int* cnt    = offs + B_ * N_ + 4;
    int* cursor = cnt + B_ * N_;
    int* bsum   = cursor + B_ * N_;                      // 128
    int* bbase  = bsum + 128;                            // 128
    int* ssrc   = bbase + 128;                           // B*E
    float* ft   = h;      // alias: h dead when ft is written
    float* x3t  = mbuf;   // alias: mbuf dead when x3t written
    float* pc   = hnew;   // moments partial slabs alias hnew
    float* ps   = hnew + (size_t)B_ * C_ * K_ * 128 / 64;

    dim3 blk(256);

    bases_kernel<<<dim3((B_ * K_ * N_) / 256), blk, 0, stream>>>(nodes, modes, node_mask, bc_t, bs_t);
    fc0_kernel<<<dim3((B_ * C_ * N_) / 256), blk, 0, stream>>>(x, fc0_w, fc0_b, h);

    // ---- edge binning (once) ----
    hipMemsetAsync(cnt, 0, sizeof(int) * B_ * N_, stream);
    hist_kernel<<<dim3(B_ * E_ / 256), blk, 0, stream>>>(edges, cnt);
    scanA_kernel<<<dim3(B_ * N_ / 256), blk, 0, stream>>>(cnt, offs, bsum);
    scanB_kernel<<<dim3(1), dim3(128), 0, stream>>>(bsum, bbase);
    scanC_kernel<<<dim3(B_ * N_ / 256), blk, 0, stream>>>(offs, bbase);
    hipMemsetAsync(cursor, 0, sizeof(int) * B_ * N_, stream);
    fill_kernel<<<dim3(B_ * E_ / 256), blk, 0, stream>>>(edges, nodes, offs, cursor, ssrc, sef);

    for (int l = 0; l < L_; ++l) {
        hipMemsetAsync(xc, 0, sizeof(double) * (size_t)B_ * C_ * K_ * 2, stream);
        moments_kernel<<<dim3(B_, 2, N_ / 128), blk, 0, stream>>>(h, node_w, bc_t, bs_t, pc, ps);
        mreduce_kernel<<<dim3(B_ * C_ * K_ / 256, 4), blk, 0, stream>>>(pc, ps, xc, xs);
        x0_kernel<<<dim3(B_ * C_), blk, 0, stream>>>(h, node_mask, node_w, x0);
        mix_kernel<<<dim3(B_ * C_ * K_ / 256, 8), blk, 0, stream>>>(
            xc, xs, sp_wc + (size_t)l * C_ * C_ * K_, sp_ws + (size_t)l * C_ * C_ * K_, mtc, mts);
        mixfin_kernel<<<dim3(B_ * C_ * K_ / 256), blk, 0, stream>>>(mtc, mts, fcb, fsb);
        mix0_kernel<<<dim3(1), blk, 0, stream>>>(x0, sp_w0 + (size_t)l * C_ * C_, f0b);
        if (l != L_ - 1) {
            // fused: hnew = synth, mbuf = gelu(g_w1 @ h + g_b1)
            synth_kernel<true><<<dim3(B_, N_ / 512, C_ / 8), blk, 0, stream>>>(
                h, bc_t, bs_t, node_mask, fcb, fsb, f0b, w_w + l * C_ * C_, w_b + l * C_,
                g_w1 + l * C_ * C_, g_b1 + l * C_, hnew, mbuf);
            cgemm_kernel<false, true, false><<<dim3(B_, N_ / 512, C_ / 8), blk, 0, stream>>>(
                mbuf, g_w2 + l * C_ * C_, g_b2 + l * C_, ft);
            ker_kernel<<<dim3(B_ * E_ / 256), blk, 0, stream>>>(sef, isw + l * 4, isb + l * 2, gC, l, kerb);
            gather_kernel<<<dim3(B_ * N_ / 8), blk, 0, stream>>>(offs, ssrc, kerb, ft, x3t);
            combine_kernel<<<dim3(B_, C_ / 32, N_ / 64), blk, 0, stream>>>(hnew, x3t, h);
        } else {
            synth_kernel<false><<<dim3(B_, N_ / 512, C_ / 8), blk, 0, stream>>>(
                h, bc_t, bs_t, node_mask, fcb, fsb, f0b, w_w + l * C_ * C_, w_b + l * C_,
                g_w1, g_b1, hnew, mbuf);
        }
    }
    cgemm_kernel<true, false, true><<<dim3(B_, N_ / 512, C_ / 8), blk, 0, stream>>>(
        hnew, fc1_w, fc1_b, h);
    f2_kernel<<<dim3(B_ * N_ / 256), blk, 0, stream>>>(h, fc2_w, fc2_b, out);
}

// Round 13
// 679.204 us; speedup vs baseline: 1.1653x; 1.0132x over previous
//
#include <hip/hip_runtime.h>

constexpr int B_ = 2, N_ = 16384, E_ = 131072, C_ = 128, K_ = 64, FC_ = 128, L_ = 4;

__device__ __forceinline__ float gelu_f(float x) {
    return 0.5f * x * (1.0f + erff(x * 0.70710678118654752f));
}

// ---------------- bases: bc_t/bs_t in (B,K,N) layout, mask folded in ----------------
__global__ __launch_bounds__(256) void bases_kernel(const float* __restrict__ nodes,
                                                    const float* __restrict__ modes,
                                                    const float* __restrict__ node_mask,
                                                    float* __restrict__ bc_t,
                                                    float* __restrict__ bs_t) {
    int idx = blockIdx.x * blockDim.x + threadIdx.x;
    int n = idx & (N_ - 1);
    int k = (idx >> 14) & (K_ - 1);
    int b = idx >> 20;
    float n0 = nodes[(b * N_ + n) * 2 + 0];
    float n1 = nodes[(b * N_ + n) * 2 + 1];
    float t = n0 * modes[k * 2 + 0] + n1 * modes[k * 2 + 1];
    float s, c;
    sincosf(t, &s, &c);
    float m = node_mask[b * N_ + n];
    bc_t[idx] = c * m;
    bs_t[idx] = s * m;
}

// ---------------- fc0 ----------------
__global__ __launch_bounds__(256) void fc0_kernel(const float* __restrict__ x,
                                                  const float* __restrict__ w,
                                                  const float* __restrict__ bias,
                                                  float* __restrict__ h) {
    int idx = blockIdx.x * blockDim.x + threadIdx.x;
    int n = idx & (N_ - 1);
    int c = (idx >> 14) & (C_ - 1);
    int b = idx >> 21;
    const float* xr = x + (b * N_ + n) * 3;
    h[idx] = fmaf(xr[0], w[0 * C_ + c], fmaf(xr[1], w[1 * C_ + c], fmaf(xr[2], w[2 * C_ + c], bias[c])));
}

// ---------------- x0 moment ----------------
__global__ __launch_bounds__(256) void x0_kernel(const float* __restrict__ h,
                                                 const float* __restrict__ mask,
                                                 const float* __restrict__ wt,
                                                 double* __restrict__ x0) {
    int bc = blockIdx.x;
    int b = bc >> 7;
    int t = threadIdx.x;
    const float* hr = h + (size_t)bc * N_;
    const float* mr = mask + b * N_;
    const float* wr = wt + b * N_;
    double acc = 0.0;
    for (int n = t; n < N_; n += 256)
        acc += (double)hr[n] * (double)(mr[n] * wr[n]);
    __shared__ double red[256];
    red[t] = acc;
    __syncthreads();
    for (int s = 128; s > 0; s >>= 1) { if (t < s) red[t] += red[t + s]; __syncthreads(); }
    if (t == 0) x0[bc] = red[0];
}

// ---------------- spectral moments: fp32 inner, per-block partial slab ----------------
__global__ __launch_bounds__(256) void moments_kernel(const float* __restrict__ h,
                                                      const float* __restrict__ wt,
                                                      const float* __restrict__ bc_t,
                                                      const float* __restrict__ bs_t,
                                                      float* __restrict__ pc,
                                                      float* __restrict__ ps) {
    int b = blockIdx.x, ch = blockIdx.y, nz = blockIdx.z;
    int c0 = ch * 64, nbase = nz * 128;
    __shared__ __align__(16) float hw[64][64];
    __shared__ __align__(16) float bcn[64][64];   // [nj][k]
    __shared__ __align__(16) float bsn[64][64];
    int t = threadIdx.x;
    int kp = t & 15, cg = t >> 4;
    float ac[4][4] = {}, as[4][4] = {};   // [c][k]
    #pragma unroll
    for (int chunk = 0; chunk < 2; ++chunk) {
        int n0 = nbase + chunk * 64;
        __syncthreads();
        {
            int ci = t >> 2, ng = (t & 3) * 16;
            const float* hr = h + (size_t)(b * C_ + c0 + ci) * N_ + n0 + ng;
            const float* wr = wt + b * N_ + n0 + ng;
            #pragma unroll
            for (int j = 0; j < 4; ++j) {
                float4 h4 = *(const float4*)(hr + 4 * j);
                float4 w4 = *(const float4*)(wr + 4 * j);
                float4 p = { h4.x * w4.x, h4.y * w4.y, h4.z * w4.z, h4.w * w4.w };
                *(float4*)&hw[ci][ng + 4 * j] = p;
            }
        }
        {
            int kk = t & 63, ng = (t >> 6) * 16;
            const float* bcr = bc_t + (size_t)(b * K_ + kk) * N_ + n0 + ng;
            const float* bsr = bs_t + (size_t)(b * K_ + kk) * N_ + n0 + ng;
            #pragma unroll
            for (int j = 0; j < 4; ++j) {
                float4 vc = *(const float4*)(bcr + 4 * j);
                float4 vs = *(const float4*)(bsr + 4 * j);
                bcn[ng + 4 * j + 0][kk] = vc.x;
                bcn[ng + 4 * j + 1][kk] = vc.y;
                bcn[ng + 4 * j + 2][kk] = vc.z;
                bcn[ng + 4 * j + 3][kk] = vc.w;
                bsn[ng + 4 * j + 0][kk] = vs.x;
                bsn[ng + 4 * j + 1][kk] = vs.y;
                bsn[ng + 4 * j + 2][kk] = vs.z;
                bsn[ng + 4 * j + 3][kk] = vs.w;
            }
        }
        __syncthreads();
        #pragma unroll 4
        for (int nj = 0; nj < 64; ++nj) {
            float4 bc4 = *(const float4*)&bcn[nj][kp * 4];
            float4 bs4 = *(const float4*)&bsn[nj][kp * 4];
            #pragma unroll
            for (int r = 0; r < 4; ++r) {
                float hv = hw[cg * 4 + r][nj];
                ac[r][0] += hv * bc4.x;
                ac[r][1] += hv * bc4.y;
                ac[r][2] += hv * bc4.z;
                ac[r][3] += hv * bc4.w;
                as[r][0] -= hv * bs4.x;
                as[r][1] -= hv * bs4.y;
                as[r][2] -= hv * bs4.z;
                as[r][3] -= hv * bs4.w;
            }
        }
    }
    size_t base = ((size_t)((b * 2 + ch) * 128 + nz)) * 4096;
    #pragma unroll
    for (int r = 0; r < 4; ++r) {
        float4 vc = { ac[r][0], ac[r][1], ac[r][2], ac[r][3] };
        float4 vs = { as[r][0], as[r][1], as[r][2], as[r][3] };
        *(float4*)&pc[base + (cg * 4 + r) * 64 + kp * 4] = vc;
        *(float4*)&ps[base + (cg * 4 + r) * 64 + kp * 4] = vs;
    }
}

// ---------------- reduce partials -> f64 xc/xs ----------------
__global__ __launch_bounds__(256) void mreduce_kernel(const float* __restrict__ pc,
                                                      const float* __restrict__ ps,
                                                      double* __restrict__ xc,
                                                      double* __restrict__ xs) {
    int e = blockIdx.x * 256 + threadIdx.x;   // (b*C + c)*K + k
    int k = e & 63, c = (e >> 6) & 127, b = e >> 13;
    int ch = c >> 6, cl = c & 63;
    size_t rowbase = ((size_t)(b * 2 + ch) * 128) * 4096 + cl * 64 + k;
    int nz0 = blockIdx.y * 32;
    double sc = 0.0, ss = 0.0;
    for (int nz = nz0; nz < nz0 + 32; ++nz) {
        sc += (double)pc[rowbase + (size_t)nz * 4096];
        ss += (double)ps[rowbase + (size_t)nz * 4096];
    }
    atomicAdd(&xc[e], sc);
    atomicAdd(&xs[e], ss);
}

// ---------------- mode-mix, i-split 8x; fp32 inner (16-term chunks), f64 partial out ----------------
__global__ __launch_bounds__(256) void mix_kernel(const double* __restrict__ xc,
                                                  const double* __restrict__ xs,
                                                  const float* __restrict__ wc,
                                                  const float* __restrict__ ws,
                                                  double* __restrict__ mtc,
                                                  double* __restrict__ mts) {
    int idx = blockIdx.x * blockDim.x + threadIdx.x;   // (b*C + o)*K + k
    int ic = blockIdx.y;
    int k = idx & 63, o = (idx >> 6) & 127, b = idx >> 13;
    float afc = 0.0f, afs = 0.0f;
    #pragma unroll 4
    for (int i = ic * 16; i < ic * 16 + 16; ++i) {
        float xcv = (float)xc[(b * C_ + i) * K_ + k], xsv = (float)xs[(b * C_ + i) * K_ + k];
        float wcv = wc[(i * C_ + o) * K_ + k], wsv = ws[(i * C_ + o) * K_ + k];
        afc += xcv * wcv - xsv * wsv;
        afs += xsv * wcv + xcv * wsv;
    }
    mtc[ic * (B_ * C_ * K_) + idx] = (double)afc;
    mts[ic * (B_ * C_ * K_) + idx] = (double)afs;
}

// fc out = +2*sum, fs out = -2*sum (pre-scaled/negated for synth's pure-FMA loop)
__global__ __launch_bounds__(256) void mixfin_kernel(const double* __restrict__ mtc,
                                                     const double* __restrict__ mts,
                                                     float* __restrict__ fc,
                                                     float* __restrict__ fs) {
    int idx = blockIdx.x * blockDim.x + threadIdx.x;
    double a = 0.0, s = 0.0;
    #pragma unroll
    for (int ic = 0; ic < 8; ++ic) {
        a += mtc[ic * (B_ * C_ * K_) + idx];
        s += mts[ic * (B_ * C_ * K_) + idx];
    }
    fc[idx] = (float)(2.0 * a);
    fs[idx] = (float)(-2.0 * s);
}

// ---------------- mix0: grid(2) x 128, unrolled ----------------
__global__ __launch_bounds__(128) void mix0_kernel(const double* __restrict__ x0,
                                                   const float* __restrict__ w0,
                                                   float* __restrict__ f0) {
    int idx = blockIdx.x * 128 + threadIdx.x;
    int o = idx & 127, b = idx >> 7;
    double a = 0.0;
    #pragma unroll 8
    for (int i = 0; i < C_; ++i) a += x0[b * C_ + i] * (double)w0[i * C_ + o];
    f0[idx] = (float)a;
}

// ---------------- synthesis + Conv1d (+ optional fused gelu(W1@h)) ----------------
// NO LDS: coefficients read via wave-uniform global addresses -> s_load/SGPR.
// grid (B, N/512, C/8), 2n/thread float2.   [round-9 exact — do not perturb]
template <bool FUSE_M>
__global__ __launch_bounds__(256) void synth_kernel(const float* __restrict__ h,
                                                    const float* __restrict__ bc_t,
                                                    const float* __restrict__ bs_t,
                                                    const float* __restrict__ mask,
                                                    const float* __restrict__ fc,
                                                    const float* __restrict__ fs,
                                                    const float* __restrict__ f0,
                                                    const float* __restrict__ ww,
                                                    const float* __restrict__ wb,
                                                    const float* __restrict__ gw,
                                                    const float* __restrict__ gb,
                                                    float* __restrict__ hnew,
                                                    float* __restrict__ mout) {
    int b = blockIdx.x, n0 = blockIdx.y * 512, o0 = blockIdx.z * 8;
    int t = threadIdx.x;
    int n = n0 + t * 2;
    const float* fcp = fc + (size_t)(b * C_ + o0) * K_;   // [8][K] uniform
    const float* fsp = fs + (size_t)(b * C_ + o0) * K_;
    const float* wwp = ww + (size_t)o0 * C_;              // [8][C] uniform
    const float* gwp = FUSE_M ? gw + (size_t)o0 * C_ : nullptr;
    float2 mv = *(const float2*)(mask + b * N_ + n);
    float acc[8][2];
    float accm[8][2];
    #pragma unroll
    for (int oi = 0; oi < 8; ++oi) {
        float f0v = f0[b * C_ + o0 + oi];
        float wbv = wb[o0 + oi];
        acc[oi][0] = f0v * mv.x + wbv;
        acc[oi][1] = f0v * mv.y + wbv;
        if (FUSE_M) {
            float gbv = gb[o0 + oi];
            accm[oi][0] = gbv;
            accm[oi][1] = gbv;
        }
    }
    #pragma unroll 4
    for (int kk = 0; kk < K_; ++kk) {
        float2 bc2 = *(const float2*)(bc_t + (size_t)(b * K_ + kk) * N_ + n);
        float2 bs2 = *(const float2*)(bs_t + (size_t)(b * K_ + kk) * N_ + n);
        #pragma unroll
        for (int oi = 0; oi < 8; ++oi) {
            float fcv = fcp[oi * K_ + kk];   // uniform -> SGPR
            float fsv = fsp[oi * K_ + kk];   // pre-negated/scaled
            acc[oi][0] += fcv * bc2.x + fsv * bs2.x;
            acc[oi][1] += fcv * bc2.y + fsv * bs2.y;
        }
    }
    #pragma unroll 4
    for (int ii = 0; ii < C_; ++ii) {
        float2 hv = *(const float2*)(h + (size_t)(b * C_ + ii) * N_ + n);
        #pragma unroll
        for (int oi = 0; oi < 8; ++oi) {
            float wv = wwp[oi * C_ + ii];    // uniform -> SGPR
            acc[oi][0] += wv * hv.x;
            acc[oi][1] += wv * hv.y;
            if (FUSE_M) {
                float gv = gwp[oi * C_ + ii];
                accm[oi][0] += gv * hv.x;
                accm[oi][1] += gv * hv.y;
            }
        }
    }
    #pragma unroll
    for (int oi = 0; oi < 8; ++oi) {
        float2 st = { acc[oi][0], acc[oi][1] };
        *(float2*)(hnew + (size_t)(b * C_ + o0 + oi) * N_ + n) = st;
        if (FUSE_M) {
            float2 sm = { gelu_f(accm[oi][0]), gelu_f(accm[oi][1]) };
            *(float2*)(mout + (size_t)(b * C_ + o0 + oi) * N_ + n) = sm;
        }
    }
}

// ---------------- channel GEMM: out = act(W @ in + b); no LDS, uniform scalar W ----------------
// grid (B, N/512, C/8).   [round-9 exact]
template <bool GELU_ACT, bool TRANSPOSED_OUT, bool W_TRANSPOSED>
__global__ __launch_bounds__(256) void cgemm_kernel(const float* __restrict__ in,
                                                    const float* __restrict__ W,
                                                    const float* __restrict__ bias,
                                                    float* __restrict__ out) {
    int b = blockIdx.x, n0 = blockIdx.y * 512, o0 = blockIdx.z * 8;
    int t = threadIdx.x;
    int n = n0 + t * 2;
    float acc[8][2];
    #pragma unroll
    for (int oi = 0; oi < 8; ++oi) {
        float bv = bias[o0 + oi];
        acc[oi][0] = bv;
        acc[oi][1] = bv;
    }
    #pragma unroll 4
    for (int ii = 0; ii < C_; ++ii) {
        float2 v = *(const float2*)(in + (size_t)(b * C_ + ii) * N_ + n);
        #pragma unroll
        for (int oi = 0; oi < 8; ++oi) {
            float wv = W_TRANSPOSED ? W[ii * C_ + (o0 + oi)] : W[(o0 + oi) * C_ + ii];  // uniform
            acc[oi][0] += wv * v.x;
            acc[oi][1] += wv * v.y;
        }
    }
    if (TRANSPOSED_OUT) {
        #pragma unroll
        for (int j = 0; j < 2; ++j) {
            float* orow = out + (size_t)(b * N_ + n + j) * C_ + o0;
            #pragma unroll
            for (int q = 0; q < 2; ++q) {
                float4 v4;
                v4.x = GELU_ACT ? gelu_f(acc[q * 4 + 0][j]) : acc[q * 4 + 0][j];
                v4.y = GELU_ACT ? gelu_f(acc[q * 4 + 1][j]) : acc[q * 4 + 1][j];
                v4.z = GELU_ACT ? gelu_f(acc[q * 4 + 2][j]) : acc[q * 4 + 2][j];
                v4.w = GELU_ACT ? gelu_f(acc[q * 4 + 3][j]) : acc[q * 4 + 3][j];
                *(float4*)(orow + q * 4) = v4;
            }
        }
    } else {
        #pragma unroll
        for (int oi = 0; oi < 8; ++oi) {
            float2 v2;
            v2.x = GELU_ACT ? gelu_f(acc[oi][0]) : acc[oi][0];
            v2.y = GELU_ACT ? gelu_f(acc[oi][1]) : acc[oi][1];
            *(float2*)(out + (size_t)(b * C_ + o0 + oi) * N_ + n) = v2;
        }
    }
}

// ---------------- final: fused gelu(fc1) + fc2 contraction via atomics ----------------
// grid (B, N/512, C/8); each block contributes its 8-o partial to out[b][n].
__global__ __launch_bounds__(256) void cgemm_f2_kernel(const float* __restrict__ in,
                                                       const float* __restrict__ W,    // fc1_w (C x FC)
                                                       const float* __restrict__ bias, // fc1_b
                                                       const float* __restrict__ w2,   // fc2_w (FC)
                                                       const float* __restrict__ b2,   // fc2_b
                                                       float* __restrict__ out) {
    int b = blockIdx.x, n0 = blockIdx.y * 512, o0 = blockIdx.z * 8;
    int t = threadIdx.x;
    int n = n0 + t * 2;
    float acc[8][2];
    #pragma unroll
    for (int oi = 0; oi < 8; ++oi) {
        float bv = bias[o0 + oi];
        acc[oi][0] = bv;
        acc[oi][1] = bv;
    }
    #pragma unroll 4
    for (int ii = 0; ii < C_; ++ii) {
        float2 v = *(const float2*)(in + (size_t)(b * C_ + ii) * N_ + n);
        #pragma unroll
        for (int oi = 0; oi < 8; ++oi) {
            float wv = W[ii * FC_ + (o0 + oi)];   // uniform -> SGPR
            acc[oi][0] += wv * v.x;
            acc[oi][1] += wv * v.y;
        }
    }
    float p0 = (blockIdx.z == 0) ? b2[0] : 0.0f;
    float p1 = p0;
    #pragma unroll
    for (int oi = 0; oi < 8; ++oi) {
        float wv = w2[o0 + oi];                   // uniform -> SGPR
        p0 += gelu_f(acc[oi][0]) * wv;
        p1 += gelu_f(acc[oi][1]) * wv;
    }
    atomicAdd(&out[b * N_ + n], p0);
    atomicAdd(&out[b * N_ + n + 1], p1);
}

// ---------------- edge binning (once per call) ----------------
__global__ __launch_bounds__(256) void hist_kernel(const int* __restrict__ edges,
                                                   int* __restrict__ cnt) {
    int be = blockIdx.x * 256 + threadIdx.x;
    int b = be >> 17;
    int tgt = edges[(size_t)be * 2 + 1];
    atomicAdd(&cnt[b * N_ + tgt], 1);
}

__global__ __launch_bounds__(256) void scanA_kernel(const int* __restrict__ cnt,
                                                    int* __restrict__ offs,
                                                    int* __restrict__ bsum) {
    __shared__ int sd[256];
    int t = threadIdx.x;
    int g = blockIdx.x * 256 + t;
    int v = cnt[g];
    sd[t] = v;
    __syncthreads();
    for (int off = 1; off < 256; off <<= 1) {
        int x = (t >= off) ? sd[t - off] : 0;
        __syncthreads();
        sd[t] += x;
        __syncthreads();
    }
    offs[g] = sd[t] - v;
    if (t == 255) bsum[blockIdx.x] = sd[255];
}

__global__ __launch_bounds__(128) void scanB_kernel(const int* __restrict__ bsum,
                                                    int* __restrict__ bbase) {
    __shared__ int sd[128];
    int t = threadIdx.x;
    int v = bsum[t];
    sd[t] = v;
    __syncthreads();
    for (int off = 1; off < 128; off <<= 1) {
        int x = (t >= off) ? sd[t - off] : 0;
        __syncthreads();
        sd[t] += x;
        __syncthreads();
    }
    bbase[t] = sd[t] - v;
}

__global__ __launch_bounds__(256) void scanC_kernel(int* __restrict__ offs,
                                                    const int* __restrict__ bbase) {
    int t = threadIdx.x;
    int g = blockIdx.x * 256 + t;
    offs[g] += bbase[blockIdx.x];
    if (g == 0) offs[B_ * N_] = B_ * E_;
}

__global__ __launch_bounds__(256) void fill_kernel(const int* __restrict__ edges,
                                                   const float* __restrict__ nodes,
                                                   const int* __restrict__ offs,
                                                   int* __restrict__ cursor,
                                                   int* __restrict__ ssrc,
                                                   float2* __restrict__ sef) {
    int be = blockIdx.x * 256 + threadIdx.x;
    int b = be >> 17;
    int src = edges[(size_t)be * 2 + 0];
    int tgt = edges[(size_t)be * 2 + 1];
    int bin = b * N_ + tgt;
    int pos = atomicAdd(&cursor[bin], 1);
    int idx = offs[bin] + pos;
    ssrc[idx] = b * N_ + src;
    float2 ef;
    ef.x = nodes[(size_t)(b * N_ + src) * 2 + 0] - nodes[(size_t)(b * N_ + tgt) * 2 + 0];
    ef.y = nodes[(size_t)(b * N_ + src) * 2 + 1] - nodes[(size_t)(b * N_ + tgt) * 2 + 1];
    sef[idx] = ef;
}

// ---------------- per-target gather with fused Gaussian kernel ----------------
// 8 rows/block, float4/thread, 4-edge unroll; ker computed inline from sef.
__global__ __launch_bounds__(256) void gather_kernel(const int* __restrict__ offs,
                                                     const int* __restrict__ ssrc,
                                                     const float2* __restrict__ sef,
                                                     const float* __restrict__ isw,
                                                     const float* __restrict__ isb,
                                                     const float* __restrict__ gC,
                                                     int l,
                                                     const float* __restrict__ ft,
                                                     float* __restrict__ x3t) {
    float w00 = isw[0], w01 = isw[1], w10 = isw[2], w11 = isw[3];   // uniform -> SGPR
    float ib0 = isb[0], ib1 = isb[1], g = gC[l];
    int t = threadIdx.x;
    int row = blockIdx.x * 8 + (t >> 5);   // b*N + n
    int cq = (t & 31) * 4;
    int start = offs[row], end = offs[row + 1];
    float4 acc = { 0.f, 0.f, 0.f, 0.f };
    int j = start;
    for (; j + 4 <= end; j += 4) {
        int s0 = ssrc[j + 0], s1 = ssrc[j + 1], s2 = ssrc[j + 2], s3 = ssrc[j + 3];
        float2 e0 = sef[j + 0], e1 = sef[j + 1], e2 = sef[j + 2], e3 = sef[j + 3];
        float k0 = g * expf(e0.x * (w00 * e0.x + w01 * e0.y + ib0) + e0.y * (w10 * e0.x + w11 * e0.y + ib1));
        float k1 = g * expf(e1.x * (w00 * e1.x + w01 * e1.y + ib0) + e1.y * (w10 * e1.x + w11 * e1.y + ib1));
        float k2 = g * expf(e2.x * (w00 * e2.x + w01 * e2.y + ib0) + e2.y * (w10 * e2.x + w11 * e2.y + ib1));
        float k3 = g * expf(e3.x * (w00 * e3.x + w01 * e3.y + ib0) + e3.y * (w10 * e3.x + w11 * e3.y + ib1));
        float4 v0 = *(const float4*)(ft + (size_t)s0 * C_ + cq);
        float4 v1 = *(const float4*)(ft + (size_t)s1 * C_ + cq);
        float4 v2 = *(const float4*)(ft + (size_t)s2 * C_ + cq);
        float4 v3 = *(const float4*)(ft + (size_t)s3 * C_ + cq);
        acc.x += k0 * v0.x + k1 * v1.x + k2 * v2.x + k3 * v3.x;
        acc.y += k0 * v0.y + k1 * v1.y + k2 * v2.y + k3 * v3.y;
        acc.z += k0 * v0.z + k1 * v1.z + k2 * v2.z + k3 * v3.z;
        acc.w += k0 * v0.w + k1 * v1.w + k2 * v2.w + k3 * v3.w;
    }
    for (; j < end; ++j) {
        int s = ssrc[j];
        float2 e = sef[j];
        float kv = g * expf(e.x * (w00 * e.x + w01 * e.y + ib0) + e.y * (w10 * e.x + w11 * e.y + ib1));
        float4 v = *(const float4*)(ft + (size_t)s * C_ + cq);
        acc.x += kv * v.x;
        acc.y += kv * v.y;
        acc.z += kv * v.z;
        acc.w += kv * v.w;
    }
    *(float4*)(x3t + (size_t)row * C_ + cq) = acc;
}

// ---------------- combine: h = gelu(hnew) + gelu(x3t^T) ----------------
__global__ __launch_bounds__(256) void combine_kernel(const float* __restrict__ hnew,
                                                      const float* __restrict__ x3t,
                                                      float* __restrict__ h) {
    int b = blockIdx.x, c0 = blockIdx.y * 32, n0 = blockIdx.z * 64;
    __shared__ float tl[32][65];
    int t = threadIdx.x;
    int ci = t & 31, nj = t >> 5;
    #pragma unroll
    for (int p = 0; p < 8; ++p) {
        int n = n0 + p * 8 + nj;
        tl[ci][p * 8 + nj] = x3t[(size_t)(b * N_ + n) * C_ + c0 + ci];
    }
    __syncthreads();
    int nj2 = t & 63, ci2 = t >> 6;
    #pragma unroll
    for (int p = 0; p < 8; ++p) {
        int c = c0 + p * 4 + ci2;
        int idx = (b * C_ + c) * N_ + n0 + nj2;
        h[idx] = gelu_f(hnew[idx]) + gelu_f(tl[p * 4 + ci2][nj2]);
    }
}

extern "C" void kernel_launch(void* const* d_in, const int* in_sizes, int n_in,
                              void* d_out, int out_size, void* d_ws, size_t ws_size,
                              hipStream_t stream) {
    const float* x         = (const float*)d_in[0];
    const float* node_mask = (const float*)d_in[1];
    const float* nodes     = (const float*)d_in[2];
    const float* node_w    = (const float*)d_in[3];
    const int*   edges     = (const int*)d_in[4];
    const float* modes     = (const float*)d_in[5];
    const float* fc0_w     = (const float*)d_in[6];
    const float* fc0_b     = (const float*)d_in[7];
    const float* sp_wc     = (const float*)d_in[8];
    const float* sp_ws     = (const float*)d_in[9];
    const float* sp_w0     = (const float*)d_in[10];
    const float* w_w       = (const float*)d_in[11];
    const float* w_b       = (const float*)d_in[12];
    const float* g_w1      = (const float*)d_in[13];
    const float* g_b1      = (const float*)d_in[14];
    const float* g_w2      = (const float*)d_in[15];
    const float* g_b2      = (const float*)d_in[16];
    const float* isw       = (const float*)d_in[17];
    const float* isb       = (const float*)d_in[18];
    const float* gC        = (const float*)d_in[19];
    const float* fc1_w     = (const float*)d_in[20];
    const float* fc1_b     = (const float*)d_in[21];
    const float* fc2_w     = (const float*)d_in[22];
    const float* fc2_b     = (const float*)d_in[23];
    float* out = (float*)d_out;

    // ---- workspace layout ----
    float* bc_t = (float*)d_ws;                          // 2M floats
    float* bs_t = bc_t + (size_t)B_ * K_ * N_;           // 2M
    float* h    = bs_t + (size_t)B_ * K_ * N_;           // 4M
    float* hnew = h + (size_t)B_ * C_ * N_;              // 4M
    float* mbuf = hnew + (size_t)B_ * C_ * N_;           // 4M
    double* xc  = (double*)(mbuf + (size_t)B_ * C_ * N_);
    double* xs  = xc + B_ * C_ * K_;
    double* x0  = xs + B_ * C_ * K_;                     // 256
    double* mtc = x0 + 256;                              // 8*16384
    double* mts = mtc + 8 * B_ * C_ * K_;
    float2* sef = (float2*)(mts + 8 * B_ * C_ * K_);     // B*E float2
    float* fcb  = (float*)(sef + (size_t)B_ * E_);
    float* fsb  = fcb + B_ * C_ * K_;
    float* f0b  = fsb + B_ * C_ * K_;                    // 256
    float* kerb = f0b + 256;                             // B*E (unused, layout kept)
    int* offs   = (int*)(kerb + (size_t)B_ * E_);        // B*N+1 (+pad)
    int* cnt    = offs + B_ * N_ + 4;
    int* cursor = cnt + B_ * N_;
    int* bsum   = cursor + B_ * N_;                      // 128
    int* bbase  = bsum + 128;                            // 128
    int* ssrc   = bbase + 128;                           // B*E
    float* ft   = h;      // alias: h dead when ft is written
    float* x3t  = mbuf;   // alias: mbuf dead when x3t written
    float* pc   = hnew;   // moments partial slabs alias hnew
    float* ps   = hnew + (size_t)B_ * C_ * K_ * 128 / 64;

    dim3 blk(256);

    bases_kernel<<<dim3((B_ * K_ * N_) / 256), blk, 0, stream>>>(nodes, modes, node_mask, bc_t, bs_t);
    fc0_kernel<<<dim3((B_ * C_ * N_) / 256), blk, 0, stream>>>(x, fc0_w, fc0_b, h);

    // ---- edge binning (once) ----
    hipMemsetAsync(cnt, 0, sizeof(int) * B_ * N_, stream);
    hist_kernel<<<dim3(B_ * E_ / 256), blk, 0, stream>>>(edges, cnt);
    scanA_kernel<<<dim3(B_ * N_ / 256), blk, 0, stream>>>(cnt, offs, bsum);
    scanB_kernel<<<dim3(1), dim3(128), 0, stream>>>(bsum, bbase);
    scanC_kernel<<<dim3(B_ * N_ / 256), blk, 0, stream>>>(offs, bbase);
    hipMemsetAsync(cursor, 0, sizeof(int) * B_ * N_, stream);
    fill_kernel<<<dim3(B_ * E_ / 256), blk, 0, stream>>>(edges, nodes, offs, cursor, ssrc, sef);

    for (int l = 0; l < L_; ++l) {
        hipMemsetAsync(xc, 0, sizeof(double) * (size_t)B_ * C_ * K_ * 2, stream);
        moments_kernel<<<dim3(B_, 2, N_ / 128), blk, 0, stream>>>(h, node_w, bc_t, bs_t, pc, ps);
        mreduce_kernel<<<dim3(B_ * C_ * K_ / 256, 4), blk, 0, stream>>>(pc, ps, xc, xs);
        x0_kernel<<<dim3(B_ * C_), blk, 0, stream>>>(h, node_mask, node_w, x0);
        mix_kernel<<<dim3(B_ * C_ * K_ / 256, 8), blk, 0, stream>>>(
            xc, xs, sp_wc + (size_t)l * C_ * C_ * K_, sp_ws + (size_t)l * C_ * C_ * K_, mtc, mts);
        mixfin_kernel<<<dim3(B_ * C_ * K_ / 256), blk, 0, stream>>>(mtc, mts, fcb, fsb);
        mix0_kernel<<<dim3(2), dim3(128), 0, stream>>>(x0, sp_w0 + (size_t)l * C_ * C_, f0b);
        if (l != L_ - 1) {
            // fused: hnew = synth, mbuf = gelu(g_w1 @ h + g_b1)
            synth_kernel<true><<<dim3(B_, N_ / 512, C_ / 8), blk, 0, stream>>>(
                h, bc_t, bs_t, node_mask, fcb, fsb, f0b, w_w + l * C_ * C_, w_b + l * C_,
                g_w1 + l * C_ * C_, g_b1 + l * C_, hnew, mbuf);
            cgemm_kernel<false, true, false><<<dim3(B_, N_ / 512, C_ / 8), blk, 0, stream>>>(
                mbuf, g_w2 + l * C_ * C_, g_b2 + l * C_, ft);
            gather_kernel<<<dim3(B_ * N_ / 8), blk, 0, stream>>>(
                offs, ssrc, sef, isw + l * 4, isb + l * 2, gC, l, ft, x3t);
            combine_kernel<<<dim3(B_, C_ / 32, N_ / 64), blk, 0, stream>>>(hnew, x3t, h);
        } else {
            synth_kernel<false><<<dim3(B_, N_ / 512, C_ / 8), blk, 0, stream>>>(
                h, bc_t, bs_t, node_mask, fcb, fsb, f0b, w_w + l * C_ * C_, w_b + l * C_,
                g_w1, g_b1, hnew, mbuf);
        }
    }
    hipMemsetAsync(out, 0, sizeof(float) * B_ * N_, stream);
    cgemm_f2_kernel<<<dim3(B_, N_ / 512, C_ / 8), blk, 0, stream>>>(
        hnew, fc1_w, fc1_b, fc2_w, fc2_b, out);
}

// Round 15
// 648.452 us; speedup vs baseline: 1.2205x; 1.0474x over previous
//
#include <hip/hip_runtime.h>

constexpr int B_ = 2, N_ = 16384, E_ = 131072, C_ = 128, K_ = 64, FC_ = 128, L_ = 4;

__device__ __forceinline__ float gelu_f(float x) {
    return 0.5f * x * (1.0f + erff(x * 0.70710678118654752f));
}

// ---------------- prep: bases (blocks < 8192) + fc0 (rest), bodies unchanged ----------------
__global__ __launch_bounds__(256) void prep_kernel(const float* __restrict__ nodes,
                                                   const float* __restrict__ modes,
                                                   const float* __restrict__ node_mask,
                                                   float* __restrict__ bc_t,
                                                   float* __restrict__ bs_t,
                                                   const float* __restrict__ x,
                                                   const float* __restrict__ w,
                                                   const float* __restrict__ bias,
                                                   float* __restrict__ h) {
    int bid = blockIdx.x;
    if (bid < (B_ * K_ * N_) / 256) {
        int idx = bid * 256 + threadIdx.x;
        int n = idx & (N_ - 1);
        int k = (idx >> 14) & (K_ - 1);
        int b = idx >> 20;
        float n0 = nodes[(b * N_ + n) * 2 + 0];
        float n1 = nodes[(b * N_ + n) * 2 + 1];
        float t = n0 * modes[k * 2 + 0] + n1 * modes[k * 2 + 1];
        float s, c;
        sincosf(t, &s, &c);
        float m = node_mask[b * N_ + n];
        bc_t[idx] = c * m;
        bs_t[idx] = s * m;
    } else {
        int idx = (bid - (B_ * K_ * N_) / 256) * 256 + threadIdx.x;
        int n = idx & (N_ - 1);
        int c = (idx >> 14) & (C_ - 1);
        int b = idx >> 21;
        const float* xr = x + (b * N_ + n) * 3;
        h[idx] = fmaf(xr[0], w[0 * C_ + c], fmaf(xr[1], w[1 * C_ + c], fmaf(xr[2], w[2 * C_ + c], bias[c])));
    }
}

// ---------------- spectral moments: fp32 inner, per-block partial slab ----------------
__global__ __launch_bounds__(256) void moments_kernel(const float* __restrict__ h,
                                                      const float* __restrict__ wt,
                                                      const float* __restrict__ bc_t,
                                                      const float* __restrict__ bs_t,
                                                      float* __restrict__ pc,
                                                      float* __restrict__ ps) {
    int b = blockIdx.x, ch = blockIdx.y, nz = blockIdx.z;
    int c0 = ch * 64, nbase = nz * 128;
    __shared__ __align__(16) float hw[64][64];
    __shared__ __align__(16) float bcn[64][64];   // [nj][k]
    __shared__ __align__(16) float bsn[64][64];
    int t = threadIdx.x;
    int kp = t & 15, cg = t >> 4;
    float ac[4][4] = {}, as[4][4] = {};   // [c][k]
    #pragma unroll
    for (int chunk = 0; chunk < 2; ++chunk) {
        int n0 = nbase + chunk * 64;
        __syncthreads();
        {
            int ci = t >> 2, ng = (t & 3) * 16;
            const float* hr = h + (size_t)(b * C_ + c0 + ci) * N_ + n0 + ng;
            const float* wr = wt + b * N_ + n0 + ng;
            #pragma unroll
            for (int j = 0; j < 4; ++j) {
                float4 h4 = *(const float4*)(hr + 4 * j);
                float4 w4 = *(const float4*)(wr + 4 * j);
                float4 p = { h4.x * w4.x, h4.y * w4.y, h4.z * w4.z, h4.w * w4.w };
                *(float4*)&hw[ci][ng + 4 * j] = p;
            }
        }
        {
            int kk = t & 63, ng = (t >> 6) * 16;
            const float* bcr = bc_t + (size_t)(b * K_ + kk) * N_ + n0 + ng;
            const float* bsr = bs_t + (size_t)(b * K_ + kk) * N_ + n0 + ng;
            #pragma unroll
            for (int j = 0; j < 4; ++j) {
                float4 vc = *(const float4*)(bcr + 4 * j);
                float4 vs = *(const float4*)(bsr + 4 * j);
                bcn[ng + 4 * j + 0][kk] = vc.x;
                bcn[ng + 4 * j + 1][kk] = vc.y;
                bcn[ng + 4 * j + 2][kk] = vc.z;
                bcn[ng + 4 * j + 3][kk] = vc.w;
                bsn[ng + 4 * j + 0][kk] = vs.x;
                bsn[ng + 4 * j + 1][kk] = vs.y;
                bsn[ng + 4 * j + 2][kk] = vs.z;
                bsn[ng + 4 * j + 3][kk] = vs.w;
            }
        }
        __syncthreads();
        #pragma unroll 4
        for (int nj = 0; nj < 64; ++nj) {
            float4 bc4 = *(const float4*)&bcn[nj][kp * 4];
            float4 bs4 = *(const float4*)&bsn[nj][kp * 4];
            #pragma unroll
            for (int r = 0; r < 4; ++r) {
                float hv = hw[cg * 4 + r][nj];
                ac[r][0] += hv * bc4.x;
                ac[r][1] += hv * bc4.y;
                ac[r][2] += hv * bc4.z;
                ac[r][3] += hv * bc4.w;
                as[r][0] -= hv * bs4.x;
                as[r][1] -= hv * bs4.y;
                as[r][2] -= hv * bs4.z;
                as[r][3] -= hv * bs4.w;
            }
        }
    }
    size_t base = ((size_t)((b * 2 + ch) * 128 + nz)) * 4096;
    #pragma unroll
    for (int r = 0; r < 4; ++r) {
        float4 vc = { ac[r][0], ac[r][1], ac[r][2], ac[r][3] };
        float4 vs = { as[r][0], as[r][1], as[r][2], as[r][3] };
        *(float4*)&pc[base + (cg * 4 + r) * 64 + kp * 4] = vc;
        *(float4*)&ps[base + (cg * 4 + r) * 64 + kp * 4] = vs;
    }
}

// ---------------- merged: mreduce (blocks<256: 64 x-blocks x 4 nz-groups) + x0 (blocks 256..511) ----------------
__global__ __launch_bounds__(256) void mredx0_kernel(const float* __restrict__ pc,
                                                     const float* __restrict__ ps,
                                                     const float* __restrict__ h,
                                                     const float* __restrict__ mask,
                                                     const float* __restrict__ wt,
                                                     double* __restrict__ xc,
                                                     double* __restrict__ xs,
                                                     double* __restrict__ x0) {
    __shared__ double red[256];
    int bid = blockIdx.x;
    int t = threadIdx.x;
    if (bid < 256) {
        int e = (bid & 63) * 256 + t;   // (b*C + c)*K + k, e in [0, 16384)
        int k = e & 63, c = (e >> 6) & 127, b = e >> 13;
        int ch = c >> 6, cl = c & 63;
        size_t rowbase = ((size_t)(b * 2 + ch) * 128) * 4096 + cl * 64 + k;
        int nz0 = (bid >> 6) * 32;      // 4 nz-groups x 32
        double sc = 0.0, ss = 0.0;
        for (int nz = nz0; nz < nz0 + 32; ++nz) {
            sc += (double)pc[rowbase + (size_t)nz * 4096];
            ss += (double)ps[rowbase + (size_t)nz * 4096];
        }
        atomicAdd(&xc[e], sc);
        atomicAdd(&xs[e], ss);
    } else {
        int bc = bid - 256;             // b*C + c in [0, 256)
        int b = bc >> 7;
        const float* hr = h + (size_t)bc * N_;
        const float* mr = mask + b * N_;
        const float* wr = wt + b * N_;
        double acc = 0.0;
        for (int n = t; n < N_; n += 256)
            acc += (double)hr[n] * (double)(mr[n] * wr[n]);
        red[t] = acc;
        __syncthreads();
        for (int s = 128; s > 0; s >>= 1) { if (t < s) red[t] += red[t + s]; __syncthreads(); }
        if (t == 0) x0[bc] = red[0];
    }
}

// ---------------- mode-mix, i-split 8x; fp32 inner (16-term chunks), f64 partial out ----------------
__global__ __launch_bounds__(256) void mix_kernel(const double* __restrict__ xc,
                                                  const double* __restrict__ xs,
                                                  const float* __restrict__ wc,
                                                  const float* __restrict__ ws,
                                                  double* __restrict__ mtc,
                                                  double* __restrict__ mts) {
    int idx = blockIdx.x * blockDim.x + threadIdx.x;   // (b*C + o)*K + k
    int ic = blockIdx.y;
    int k = idx & 63, o = (idx >> 6) & 127, b = idx >> 13;
    float afc = 0.0f, afs = 0.0f;
    #pragma unroll 4
    for (int i = ic * 16; i < ic * 16 + 16; ++i) {
        float xcv = (float)xc[(b * C_ + i) * K_ + k], xsv = (float)xs[(b * C_ + i) * K_ + k];
        float wcv = wc[(i * C_ + o) * K_ + k], wsv = ws[(i * C_ + o) * K_ + k];
        afc += xcv * wcv - xsv * wsv;
        afs += xsv * wcv + xcv * wsv;
    }
    mtc[ic * (B_ * C_ * K_) + idx] = (double)afc;
    mts[ic * (B_ * C_ * K_) + idx] = (double)afs;
}

// ---------------- merged: mixfin (blocks<64) + mix0 (block 64), bodies unchanged ----------------
__global__ __launch_bounds__(256) void mixfin0_kernel(const double* __restrict__ mtc,
                                                      const double* __restrict__ mts,
                                                      const double* __restrict__ x0,
                                                      const float* __restrict__ w0,
                                                      float* __restrict__ fc,
                                                      float* __restrict__ fs,
                                                      float* __restrict__ f0) {
    int bid = blockIdx.x;
    int t = threadIdx.x;
    if (bid < 64) {
        int idx = bid * 256 + t;
        double a = 0.0, s = 0.0;
        #pragma unroll
        for (int ic = 0; ic < 8; ++ic) {
            a += mtc[ic * (B_ * C_ * K_) + idx];
            s += mts[ic * (B_ * C_ * K_) + idx];
        }
        fc[idx] = (float)(2.0 * a);
        fs[idx] = (float)(-2.0 * s);
    } else {
        int o = t & 127, b = t >> 7;
        double a = 0.0;
        #pragma unroll 8
        for (int i = 0; i < C_; ++i) a += x0[b * C_ + i] * (double)w0[i * C_ + o];
        f0[t] = (float)a;
    }
}

// ---------------- synthesis + Conv1d (+ optional fused gelu(W1@h)) ----------------
// NO LDS: coefficients read via wave-uniform global addresses -> s_load/SGPR.
// grid (B, N/512, C/8), 2n/thread float2.   [round-9 exact — do not perturb]
template <bool FUSE_M>
__global__ __launch_bounds__(256) void synth_kernel(const float* __restrict__ h,
                                                    const float* __restrict__ bc_t,
                                                    const float* __restrict__ bs_t,
                                                    const float* __restrict__ mask,
                                                    const float* __restrict__ fc,
                                                    const float* __restrict__ fs,
                                                    const float* __restrict__ f0,
                                                    const float* __restrict__ ww,
                                                    const float* __restrict__ wb,
                                                    const float* __restrict__ gw,
                                                    const float* __restrict__ gb,
                                                    float* __restrict__ hnew,
                                                    float* __restrict__ mout) {
    int b = blockIdx.x, n0 = blockIdx.y * 512, o0 = blockIdx.z * 8;
    int t = threadIdx.x;
    int n = n0 + t * 2;
    const float* fcp = fc + (size_t)(b * C_ + o0) * K_;   // [8][K] uniform
    const float* fsp = fs + (size_t)(b * C_ + o0) * K_;
    const float* wwp = ww + (size_t)o0 * C_;              // [8][C] uniform
    const float* gwp = FUSE_M ? gw + (size_t)o0 * C_ : nullptr;
    float2 mv = *(const float2*)(mask + b * N_ + n);
    float acc[8][2];
    float accm[8][2];
    #pragma unroll
    for (int oi = 0; oi < 8; ++oi) {
        float f0v = f0[b * C_ + o0 + oi];
        float wbv = wb[o0 + oi];
        acc[oi][0] = f0v * mv.x + wbv;
        acc[oi][1] = f0v * mv.y + wbv;
        if (FUSE_M) {
            float gbv = gb[o0 + oi];
            accm[oi][0] = gbv;
            accm[oi][1] = gbv;
        }
    }
    #pragma unroll 4
    for (int kk = 0; kk < K_; ++kk) {
        float2 bc2 = *(const float2*)(bc_t + (size_t)(b * K_ + kk) * N_ + n);
        float2 bs2 = *(const float2*)(bs_t + (size_t)(b * K_ + kk) * N_ + n);
        #pragma unroll
        for (int oi = 0; oi < 8; ++oi) {
            float fcv = fcp[oi * K_ + kk];   // uniform -> SGPR
            float fsv = fsp[oi * K_ + kk];   // pre-negated/scaled
            acc[oi][0] += fcv * bc2.x + fsv * bs2.x;
            acc[oi][1] += fcv * bc2.y + fsv * bs2.y;
        }
    }
    #pragma unroll 4
    for (int ii = 0; ii < C_; ++ii) {
        float2 hv = *(const float2*)(h + (size_t)(b * C_ + ii) * N_ + n);
        #pragma unroll
        for (int oi = 0; oi < 8; ++oi) {
            float wv = wwp[oi * C_ + ii];    // uniform -> SGPR
            acc[oi][0] += wv * hv.x;
            acc[oi][1] += wv * hv.y;
            if (FUSE_M) {
                float gv = gwp[oi * C_ + ii];
                accm[oi][0] += gv * hv.x;
                accm[oi][1] += gv * hv.y;
            }
        }
    }
    #pragma unroll
    for (int oi = 0; oi < 8; ++oi) {
        float2 st = { acc[oi][0], acc[oi][1] };
        *(float2*)(hnew + (size_t)(b * C_ + o0 + oi) * N_ + n) = st;
        if (FUSE_M) {
            float2 sm = { gelu_f(accm[oi][0]), gelu_f(accm[oi][1]) };
            *(float2*)(mout + (size_t)(b * C_ + o0 + oi) * N_ + n) = sm;
        }
    }
}

// ---------------- channel GEMM: out = act(W @ in + b); no LDS, uniform scalar W ----------------
// grid (B, N/512, C/8).   [round-9 exact]
template <bool GELU_ACT, bool TRANSPOSED_OUT, bool W_TRANSPOSED>
__global__ __launch_bounds__(256) void cgemm_kernel(const float* __restrict__ in,
                                                    const float* __restrict__ W,
                                                    const float* __restrict__ bias,
                                                    float* __restrict__ out) {
    int b = blockIdx.x, n0 = blockIdx.y * 512, o0 = blockIdx.z * 8;
    int t = threadIdx.x;
    int n = n0 + t * 2;
    float acc[8][2];
    #pragma unroll
    for (int oi = 0; oi < 8; ++oi) {
        float bv = bias[o0 + oi];
        acc[oi][0] = bv;
        acc[oi][1] = bv;
    }
    #pragma unroll 4
    for (int ii = 0; ii < C_; ++ii) {
        float2 v = *(const float2*)(in + (size_t)(b * C_ + ii) * N_ + n);
        #pragma unroll
        for (int oi = 0; oi < 8; ++oi) {
            float wv = W_TRANSPOSED ? W[ii * C_ + (o0 + oi)] : W[(o0 + oi) * C_ + ii];  // uniform
            acc[oi][0] += wv * v.x;
            acc[oi][1] += wv * v.y;
        }
    }
    if (TRANSPOSED_OUT) {
        #pragma unroll
        for (int j = 0; j < 2; ++j) {
            float* orow = out + (size_t)(b * N_ + n + j) * C_ + o0;
            #pragma unroll
            for (int q = 0; q < 2; ++q) {
                float4 v4;
                v4.x = GELU_ACT ? gelu_f(acc[q * 4 + 0][j]) : acc[q * 4 + 0][j];
                v4.y = GELU_ACT ? gelu_f(acc[q * 4 + 1][j]) : acc[q * 4 + 1][j];
                v4.z = GELU_ACT ? gelu_f(acc[q * 4 + 2][j]) : acc[q * 4 + 2][j];
                v4.w = GELU_ACT ? gelu_f(acc[q * 4 + 3][j]) : acc[q * 4 + 3][j];
                *(float4*)(orow + q * 4) = v4;
            }
        }
    } else {
        #pragma unroll
        for (int oi = 0; oi < 8; ++oi) {
            float2 v2;
            v2.x = GELU_ACT ? gelu_f(acc[oi][0]) : acc[oi][0];
            v2.y = GELU_ACT ? gelu_f(acc[oi][1]) : acc[oi][1];
            *(float2*)(out + (size_t)(b * C_ + o0 + oi) * N_ + n) = v2;
        }
    }
}

// ---------------- final: fused gelu(fc1) + fc2 contraction via atomics ----------------
__global__ __launch_bounds__(256) void cgemm_f2_kernel(const float* __restrict__ in,
                                                       const float* __restrict__ W,    // fc1_w (C x FC)
                                                       const float* __restrict__ bias, // fc1_b
                                                       const float* __restrict__ w2,   // fc2_w (FC)
                                                       const float* __restrict__ b2,   // fc2_b
                                                       float* __restrict__ out) {
    int b = blockIdx.x, n0 = blockIdx.y * 512, o0 = blockIdx.z * 8;
    int t = threadIdx.x;
    int n = n0 + t * 2;
    float acc[8][2];
    #pragma unroll
    for (int oi = 0; oi < 8; ++oi) {
        float bv = bias[o0 + oi];
        acc[oi][0] = bv;
        acc[oi][1] = bv;
    }
    #pragma unroll 4
    for (int ii = 0; ii < C_; ++ii) {
        float2 v = *(const float2*)(in + (size_t)(b * C_ + ii) * N_ + n);
        #pragma unroll
        for (int oi = 0; oi < 8; ++oi) {
            float wv = W[ii * FC_ + (o0 + oi)];   // uniform -> SGPR
            acc[oi][0] += wv * v.x;
            acc[oi][1] += wv * v.y;
        }
    }
    float p0 = (blockIdx.z == 0) ? b2[0] : 0.0f;
    float p1 = p0;
    #pragma unroll
    for (int oi = 0; oi < 8; ++oi) {
        float wv = w2[o0 + oi];                   // uniform -> SGPR
        p0 += gelu_f(acc[oi][0]) * wv;
        p1 += gelu_f(acc[oi][1]) * wv;
    }
    atomicAdd(&out[b * N_ + n], p0);
    atomicAdd(&out[b * N_ + n + 1], p1);
}

// ---------------- edge binning (once per call) ----------------
__global__ __launch_bounds__(256) void hist_kernel(const int* __restrict__ edges,
                                                   int* __restrict__ cnt) {
    int be = blockIdx.x * 256 + threadIdx.x;
    int b = be >> 17;
    int tgt = edges[(size_t)be * 2 + 1];
    atomicAdd(&cnt[b * N_ + tgt], 1);
}

__global__ __launch_bounds__(256) void scanA_kernel(const int* __restrict__ cnt,
                                                    int* __restrict__ offs,
                                                    int* __restrict__ bsum) {
    __shared__ int sd[256];
    int t = threadIdx.x;
    int g = blockIdx.x * 256 + t;
    int v = cnt[g];
    sd[t] = v;
    __syncthreads();
    for (int off = 1; off < 256; off <<= 1) {
        int x = (t >= off) ? sd[t - off] : 0;
        __syncthreads();
        sd[t] += x;
        __syncthreads();
    }
    offs[g] = sd[t] - v;
    if (t == 255) bsum[blockIdx.x] = sd[255];
}

__global__ __launch_bounds__(128) void scanB_kernel(const int* __restrict__ bsum,
                                                    int* __restrict__ bbase) {
    __shared__ int sd[128];
    int t = threadIdx.x;
    int v = bsum[t];
    sd[t] = v;
    __syncthreads();
    for (int off = 1; off < 128; off <<= 1) {
        int x = (t >= off) ? sd[t - off] : 0;
        __syncthreads();
        sd[t] += x;
        __syncthreads();
    }
    bbase[t] = sd[t] - v;
}

__global__ __launch_bounds__(256) void scanC_kernel(int* __restrict__ offs,
                                                    const int* __restrict__ bbase) {
    int t = threadIdx.x;
    int g = blockIdx.x * 256 + t;
    offs[g] += bbase[blockIdx.x];
    if (g == 0) offs[B_ * N_] = B_ * E_;
}

__global__ __launch_bounds__(256) void fill_kernel(const int* __restrict__ edges,
                                                   const float* __restrict__ nodes,
                                                   const int* __restrict__ offs,
                                                   int* __restrict__ cursor,
                                                   int* __restrict__ ssrc,
                                                   float2* __restrict__ sef) {
    int be = blockIdx.x * 256 + threadIdx.x;
    int b = be >> 17;
    int src = edges[(size_t)be * 2 + 0];
    int tgt = edges[(size_t)be * 2 + 1];
    int bin = b * N_ + tgt;
    int pos = atomicAdd(&cursor[bin], 1);
    int idx = offs[bin] + pos;
    ssrc[idx] = b * N_ + src;
    float2 ef;
    ef.x = nodes[(size_t)(b * N_ + src) * 2 + 0] - nodes[(size_t)(b * N_ + tgt) * 2 + 0];
    ef.y = nodes[(size_t)(b * N_ + src) * 2 + 1] - nodes[(size_t)(b * N_ + tgt) * 2 + 1];
    sef[idx] = ef;
}

// ---------------- per-target gather with fused Gaussian kernel ----------------
__global__ __launch_bounds__(256) void gather_kernel(const int* __restrict__ offs,
                                                     const int* __restrict__ ssrc,
                                                     const float2* __restrict__ sef,
                                                     const float* __restrict__ isw,
                                                     const float* __restrict__ isb,
                                                     const float* __restrict__ gC,
                                                     int l,
                                                     const float* __restrict__ ft,
                                                     float* __restrict__ x3t) {
    float w00 = isw[0], w01 = isw[1], w10 = isw[2], w11 = isw[3];   // uniform -> SGPR
    float ib0 = isb[0], ib1 = isb[1], g = gC[l];
    int t = threadIdx.x;
    int row = blockIdx.x * 8 + (t >> 5);   // b*N + n
    int cq = (t & 31) * 4;
    int start = offs[row], end = offs[row + 1];
    float4 acc = { 0.f, 0.f, 0.f, 0.f };
    int j = start;
    for (; j + 4 <= end; j += 4) {
        int s0 = ssrc[j + 0], s1 = ssrc[j + 1], s2 = ssrc[j + 2], s3 = ssrc[j + 3];
        float2 e0 = sef[j + 0], e1 = sef[j + 1], e2 = sef[j + 2], e3 = sef[j + 3];
        float k0 = g * expf(e0.x * (w00 * e0.x + w01 * e0.y + ib0) + e0.y * (w10 * e0.x + w11 * e0.y + ib1));
        float k1 = g * expf(e1.x * (w00 * e1.x + w01 * e1.y + ib0) + e1.y * (w10 * e1.x + w11 * e1.y + ib1));
        float k2 = g * expf(e2.x * (w00 * e2.x + w01 * e2.y + ib0) + e2.y * (w10 * e2.x + w11 * e2.y + ib1));
        float k3 = g * expf(e3.x * (w00 * e3.x + w01 * e3.y + ib0) + e3.y * (w10 * e3.x + w11 * e3.y + ib1));
        float4 v0 = *(const float4*)(ft + (size_t)s0 * C_ + cq);
        float4 v1 = *(const float4*)(ft + (size_t)s1 * C_ + cq);
        float4 v2 = *(const float4*)(ft + (size_t)s2 * C_ + cq);
        float4 v3 = *(const float4*)(ft + (size_t)s3 * C_ + cq);
        acc.x += k0 * v0.x + k1 * v1.x + k2 * v2.x + k3 * v3.x;
        acc.y += k0 * v0.y + k1 * v1.y + k2 * v2.y + k3 * v3.y;
        acc.z += k0 * v0.z + k1 * v1.z + k2 * v2.z + k3 * v3.z;
        acc.w += k0 * v0.w + k1 * v1.w + k2 * v2.w + k3 * v3.w;
    }
    for (; j < end; ++j) {
        int s = ssrc[j];
        float2 e = sef[j];
        float kv = g * expf(e.x * (w00 * e.x + w01 * e.y + ib0) + e.y * (w10 * e.x + w11 * e.y + ib1));
        float4 v = *(const float4*)(ft + (size_t)s * C_ + cq);
        acc.x += kv * v.x;
        acc.y += kv * v.y;
        acc.z += kv * v.z;
        acc.w += kv * v.w;
    }
    *(float4*)(x3t + (size_t)row * C_ + cq) = acc;
}

// ---------------- combine: h = gelu(hnew) + gelu(x3t^T) ----------------
__global__ __launch_bounds__(256) void combine_kernel(const float* __restrict__ hnew,
                                                      const float* __restrict__ x3t,
                                                      float* __restrict__ h) {
    int b = blockIdx.x, c0 = blockIdx.y * 32, n0 = blockIdx.z * 64;
    __shared__ float tl[32][65];
    int t = threadIdx.x;
    int ci = t & 31, nj = t >> 5;
    #pragma unroll
    for (int p = 0; p < 8; ++p) {
        int n = n0 + p * 8 + nj;
        tl[ci][p * 8 + nj] = x3t[(size_t)(b * N_ + n) * C_ + c0 + ci];
    }
    __syncthreads();
    int nj2 = t & 63, ci2 = t >> 6;
    #pragma unroll
    for (int p = 0; p < 8; ++p) {
        int c = c0 + p * 4 + ci2;
        int idx = (b * C_ + c) * N_ + n0 + nj2;
        h[idx] = gelu_f(hnew[idx]) + gelu_f(tl[p * 4 + ci2][nj2]);
    }
}

extern "C" void kernel_launch(void* const* d_in, const int* in_sizes, int n_in,
                              void* d_out, int out_size, void* d_ws, size_t ws_size,
                              hipStream_t stream) {
    const float* x         = (const float*)d_in[0];
    const float* node_mask = (const float*)d_in[1];
    const float* nodes     = (const float*)d_in[2];
    const float* node_w    = (const float*)d_in[3];
    const int*   edges     = (const int*)d_in[4];
    const float* modes     = (const float*)d_in[5];
    const float* fc0_w     = (const float*)d_in[6];
    const float* fc0_b     = (const float*)d_in[7];
    const float* sp_wc     = (const float*)d_in[8];
    const float* sp_ws     = (const float*)d_in[9];
    const float* sp_w0     = (const float*)d_in[10];
    const float* w_w       = (const float*)d_in[11];
    const float* w_b       = (const float*)d_in[12];
    const float* g_w1      = (const float*)d_in[13];
    const float* g_b1      = (const float*)d_in[14];
    const float* g_w2      = (const float*)d_in[15];
    const float* g_b2      = (const float*)d_in[16];
    const float* isw       = (const float*)d_in[17];
    const float* isb       = (const float*)d_in[18];
    const float* gC        = (const float*)d_in[19];
    const float* fc1_w     = (const float*)d_in[20];
    const float* fc1_b     = (const float*)d_in[21];
    const float* fc2_w     = (const float*)d_in[22];
    const float* fc2_b     = (const float*)d_in[23];
    float* out = (float*)d_out;

    // ---- workspace layout ----
    float* bc_t = (float*)d_ws;                          // 2M floats
    float* bs_t = bc_t + (size_t)B_ * K_ * N_;           // 2M
    float* h    = bs_t + (size_t)B_ * K_ * N_;           // 4M
    float* hnew = h + (size_t)B_ * C_ * N_;              // 4M
    float* mbuf = hnew + (size_t)B_ * C_ * N_;           // 4M
    double* xcs = (double*)(mbuf + (size_t)B_ * C_ * N_);   // 4 layers x (xc,xs)
    double* x0  = xcs + (size_t)4 * 2 * B_ * C_ * K_;    // 256 doubles
    double* mtc = x0 + 256;                              // 8*16384
    double* mts = mtc + 8 * B_ * C_ * K_;
    float2* sef = (float2*)(mts + 8 * B_ * C_ * K_);     // B*E float2
    float* fcb  = (float*)(sef + (size_t)B_ * E_);
    float* fsb  = fcb + B_ * C_ * K_;
    float* f0b  = fsb + B_ * C_ * K_;                    // 256
    int* offs   = (int*)(f0b + 256);                     // B*N+1 (+pad)
    int* cnt    = offs + B_ * N_ + 4;
    int* cursor = cnt + B_ * N_;
    int* bsum   = cursor + B_ * N_;                      // 128
    int* bbase  = bsum + 128;                            // 128
    int* ssrc   = bbase + 128;                           // B*E
    float* ft   = h;      // alias: h dead when ft is written
    float* x3t  = mbuf;   // alias: mbuf dead when x3t written
    float* pc   = hnew;   // moments partial slabs alias hnew
    float* ps   = hnew + (size_t)B_ * C_ * K_ * 128 / 64;

    dim3 blk(256);

    prep_kernel<<<dim3((B_ * K_ * N_) / 256 + (B_ * C_ * N_) / 256), blk, 0, stream>>>(
        nodes, modes, node_mask, bc_t, bs_t, x, fc0_w, fc0_b, h);

    // ---- edge binning (once) ----
    hipMemsetAsync(cnt, 0, sizeof(int) * B_ * N_, stream);
    hist_kernel<<<dim3(B_ * E_ / 256), blk, 0, stream>>>(edges, cnt);
    scanA_kernel<<<dim3(B_ * N_ / 256), blk, 0, stream>>>(cnt, offs, bsum);
    scanB_kernel<<<dim3(1), dim3(128), 0, stream>>>(bsum, bbase);
    scanC_kernel<<<dim3(B_ * N_ / 256), blk, 0, stream>>>(offs, bbase);
    hipMemsetAsync(cursor, 0, sizeof(int) * B_ * N_, stream);
    fill_kernel<<<dim3(B_ * E_ / 256), blk, 0, stream>>>(edges, nodes, offs, cursor, ssrc, sef);

    // one memset for all 4 layers' xc/xs slabs
    hipMemsetAsync(xcs, 0, sizeof(double) * (size_t)4 * 2 * B_ * C_ * K_, stream);

    for (int l = 0; l < L_; ++l) {
        double* xc = xcs + (size_t)l * 2 * B_ * C_ * K_;
        double* xs = xc + B_ * C_ * K_;
        moments_kernel<<<dim3(B_, 2, N_ / 128), blk, 0, stream>>>(h, node_w, bc_t, bs_t, pc, ps);
        mredx0_kernel<<<dim3(512), blk, 0, stream>>>(pc, ps, h, node_mask, node_w, xc, xs, x0);
        mix_kernel<<<dim3(B_ * C_ * K_ / 256, 8), blk, 0, stream>>>(
            xc, xs, sp_wc + (size_t)l * C_ * C_ * K_, sp_ws + (size_t)l * C_ * C_ * K_, mtc, mts);
        mixfin0_kernel<<<dim3(65), blk, 0, stream>>>(mtc, mts, x0, sp_w0 + (size_t)l * C_ * C_, fcb, fsb, f0b);
        if (l != L_ - 1) {
            synth_kernel<true><<<dim3(B_, N_ / 512, C_ / 8), blk, 0, stream>>>(
                h, bc_t, bs_t, node_mask, fcb, fsb, f0b, w_w + l * C_ * C_, w_b + l * C_,
                g_w1 + l * C_ * C_, g_b1 + l * C_, hnew, mbuf);
            cgemm_kernel<false, true, false><<<dim3(B_, N_ / 512, C_ / 8), blk, 0, stream>>>(
                mbuf, g_w2 + l * C_ * C_, g_b2 + l * C_, ft);
            gather_kernel<<<dim3(B_ * N_ / 8), blk, 0, stream>>>(
                offs, ssrc, sef, isw + l * 4, isb + l * 2, gC, l, ft, x3t);
            combine_kernel<<<dim3(B_, C_ / 32, N_ / 64), blk, 0, stream>>>(hnew, x3t, h);
        } else {
            synth_kernel<false><<<dim3(B_, N_ / 512, C_ / 8), blk, 0, stream>>>(
                h, bc_t, bs_t, node_mask, fcb, fsb, f0b, w_w + l * C_ * C_, w_b + l * C_,
                g_w1, g_b1, hnew, mbuf);
        }
    }
    hipMemsetAsync(out, 0, sizeof(float) * B_ * N_, stream);
    cgemm_f2_kernel<<<dim3(B_, N_ / 512, C_ / 8), blk, 0, stream>>>(
        hnew, fc1_w, fc1_b, fc2_w, fc2_b, out);
}